// Round 6
// baseline (393.669 us; speedup 1.0000x reference)
//
#include <hip/hip_runtime.h>
#include <hip/hip_bf16.h>
#include <math.h>

#define NN 10000
#define NE 131072

typedef __attribute__((ext_vector_type(8))) short short8;
typedef __attribute__((ext_vector_type(4))) float f32x4;

__device__ __forceinline__ float silu_f(float x) {
    return x / (1.0f + __expf(-x));
}

// round-to-nearest-even f32 -> bf16 (finite inputs only)
__device__ __forceinline__ unsigned short f2bf(float f) {
    unsigned int u = __float_as_uint(f);
    u += 0x7FFFu + ((u >> 16) & 1u);
    return (unsigned short)(u >> 16);
}

// packed pair via HW v_cvt_pk_bf16_f32 (x = low half)
__device__ __forceinline__ unsigned int pk_bf16(float lo, float hi) {
    __hip_bfloat162 h = __float22bfloat162_rn(float2{lo, hi});
    return *reinterpret_cast<unsigned int*>(&h);
}

// ---------------------------------------------------------------------------
// Sort machinery: counting sort of edges by dst (10000 bins).
// ---------------------------------------------------------------------------
__global__ __launch_bounds__(256)
void hist_kernel(const int* __restrict__ edst, int* __restrict__ hist)
{
    int e = blockIdx.x * 256 + threadIdx.x;
    if (e < NE) atomicAdd(&hist[edst[e]], 1);
}

__global__ __launch_bounds__(256)
void scan_kernel(const int* __restrict__ hist, int* __restrict__ offsets)
{
    __shared__ int part[256];
    int tid = threadIdx.x;
    int base = tid * 40, s = 0;
    for (int r = 0; r < 40; ++r) {
        int idx = base + r;
        if (idx < NN) s += hist[idx];
    }
    part[tid] = s;
    __syncthreads();
    if (tid == 0) {
        int run = 0;
        for (int i = 0; i < 256; ++i) { int t = part[i]; part[i] = run; run += t; }
        offsets[NN] = run;   // == NE
    }
    __syncthreads();
    int run = part[tid];
    for (int r = 0; r < 40; ++r) {
        int idx = base + r;
        if (idx < NN) { offsets[idx] = run; run += hist[idx]; }
    }
}

__global__ __launch_bounds__(256)
void rank_kernel(const int* __restrict__ edst, const int* __restrict__ offsets,
                 int* __restrict__ poscnt, int* __restrict__ sortidx)
{
    int e = blockIdx.x * 256 + threadIdx.x;
    if (e >= NE) return;
    int d = edst[e];
    int p = offsets[d] + atomicAdd(&poscnt[d], 1);
    sortidx[p] = e;
}

// ---------------------------------------------------------------------------
// Kernel: per-node MLP  embed(16) -> 64 -> 32 -> 8  (Ai)
// ---------------------------------------------------------------------------
__global__ __launch_bounds__(256)
void node_mlp_kernel(const int* __restrict__ A,
                     const float* __restrict__ emb_tab,
                     const float* __restrict__ W1, const float* __restrict__ b1,
                     const float* __restrict__ W2, const float* __restrict__ b2,
                     const float* __restrict__ W3, const float* __restrict__ b3,
                     float* __restrict__ Ai)
{
    int n = blockIdx.x * blockDim.x + threadIdx.x;
    if (n >= NN) return;
    int a = A[n];
    float h[16];
#pragma unroll
    for (int i = 0; i < 16; ++i) h[i] = emb_tab[a * 16 + i];

    float h1[64];
#pragma unroll
    for (int j = 0; j < 64; ++j) h1[j] = b1[j];
#pragma unroll
    for (int i = 0; i < 16; ++i) {
        float hv = h[i];
#pragma unroll
        for (int j = 0; j < 64; ++j) h1[j] += hv * W1[i * 64 + j];
    }
#pragma unroll
    for (int j = 0; j < 64; ++j) h1[j] = silu_f(h1[j]);

    float h2[32];
#pragma unroll
    for (int j = 0; j < 32; ++j) h2[j] = b2[j];
#pragma unroll
    for (int i = 0; i < 64; ++i) {
        float hv = h1[i];
#pragma unroll
        for (int j = 0; j < 32; ++j) h2[j] += hv * W2[i * 32 + j];
    }
#pragma unroll
    for (int j = 0; j < 32; ++j) h2[j] = silu_f(h2[j]);

#pragma unroll
    for (int j = 0; j < 8; ++j) {
        float s = b3[j];
#pragma unroll
        for (int i = 0; i < 32; ++i) s += h2[i] * W3[i * 8 + j];
        Ai[n * 8 + j] = s;
    }
}

// ---------------------------------------------------------------------------
// Kernel: per-edge geometry + radial MLP, sorted order, CROSS-WAVE N-SPLIT.
// Block 256 thr = 4 waves = 2 edge-groups x 2 output-halves. Each wave
// computes 32 of 64 outputs per layer for its group's 64 edges; activations
// exchanged via one fp32 LDS buffer [128][67] (bit-identical fp32 math).
// Wave-uniform `half` keeps weight loads scalar (s_load). 2x the waves of
// the 1-thread-per-edge version -> latency actually hidden.
// ---------------------------------------------------------------------------
__global__ __launch_bounds__(256, 4)
void edge_mlp_kernel(const float* __restrict__ pos,
                     const int* __restrict__ batch,
                     const int* __restrict__ esrc,
                     const int* __restrict__ edst,
                     const float* __restrict__ shifts,
                     const float* __restrict__ cell,
                     const float* __restrict__ fcW1,
                     const float* __restrict__ fcW2,
                     const float* __restrict__ fcW3,
                     const int* __restrict__ sortidx,
                     int* __restrict__ esrc_s,
                     int* __restrict__ edst_s,
                     unsigned short* __restrict__ w3gT,
                     float* __restrict__ unit)
{
    __shared__ float acts[128 * 67];   // stride 67: bank=(3e+ii)%32, ~free

    const int tid   = threadIdx.x;
    const int wave  = tid >> 6;
    const int lane  = tid & 63;
    const int group = wave >> 1;       // 0,1
    const int half  = wave & 1;        // output half, wave-uniform
    const int el    = group * 64 + lane;           // local edge 0..127
    const int i     = blockIdx.x * 128 + el;       // sorted edge index

    int e = sortidx[i];
    int s = esrc[e], d = edst[e];
    int b = batch[s];
    const float* C = cell + b * 9;
    float sx = shifts[e * 3 + 0], sy = shifts[e * 3 + 1], sz = shifts[e * 3 + 2];
    float vx = pos[d * 3 + 0] - pos[s * 3 + 0] + sx * C[0] + sy * C[3] + sz * C[6];
    float vy = pos[d * 3 + 1] - pos[s * 3 + 1] + sx * C[1] + sy * C[4] + sz * C[7];
    float vz = pos[d * 3 + 2] - pos[s * 3 + 2] + sx * C[2] + sy * C[5] + sz * C[8];
    float len = sqrtf(vx * vx + vy * vy + vz * vz);
    float inv = 1.0f / fmaxf(len, 1e-9f);
    if (half == 0) {
        esrc_s[i] = s;
        edst_s[i] = d;
        unit[i * 3 + 0] = vx * inv;
        unit[i * 3 + 1] = vy * inv;
        unit[i * 3 + 2] = vz * inv;
    }

    // soft_one_hot (sqrt(10) cancels with fc_W1's /sqrt(10))
    float embv[10];
    float base = len * 2.75f;
#pragma unroll
    for (int ii = 0; ii < 10; ++ii) {
        float dd = base - (float)(ii + 1);
        embv[ii] = __expf(-dd * dd) * (1.0f / 1.12f);
    }

    float acc[32];

    // ---- layer 1: w1[half*32+j] = silu(sum_ii emb[ii]*fcW1[ii][half*32+j])
#pragma unroll
    for (int j = 0; j < 32; ++j) acc[j] = 0.f;
#pragma unroll
    for (int ii = 0; ii < 10; ++ii) {
        float hv = embv[ii];
#pragma unroll
        for (int j = 0; j < 32; ++j)
            acc[j] += hv * fcW1[ii * 64 + half * 32 + j];
    }
#pragma unroll
    for (int j = 0; j < 32; ++j)
        acts[el * 67 + half * 32 + j] = silu_f(acc[j]);

    __syncthreads();   // w1 visible

    // ---- layer 2: w2 = silu((w1 @ fcW2)/8), this wave's 32 outputs
#pragma unroll
    for (int j = 0; j < 32; ++j) acc[j] = 0.f;
#pragma unroll
    for (int ii = 0; ii < 64; ++ii) {
        float hv = acts[el * 67 + ii];
#pragma unroll
        for (int j = 0; j < 32; ++j)
            acc[j] += hv * fcW2[ii * 64 + half * 32 + j];
    }
    __syncthreads();   // all w1 reads done (WAR before overwrite)
#pragma unroll
    for (int j = 0; j < 32; ++j)
        acts[el * 67 + half * 32 + j] = silu_f(acc[j] * 0.125f);

    __syncthreads();   // w2 visible

    // ---- layer 3: w3 = silu((w2 @ fcW3)/8) -> bf16 transposed global
#pragma unroll
    for (int j = 0; j < 32; ++j) acc[j] = 0.f;
#pragma unroll
    for (int ii = 0; ii < 64; ++ii) {
        float hv = acts[el * 67 + ii];
#pragma unroll
        for (int j = 0; j < 32; ++j)
            acc[j] += hv * fcW3[ii * 64 + half * 32 + j];
    }
#pragma unroll
    for (int j = 0; j < 32; ++j)
        w3gT[(size_t)(half * 32 + j) * NE + i] = f2bf(silu_f(acc[j] * 0.125f));
}

// ---------------------------------------------------------------------------
// Kernel: build B = fc_W4 as bf16 MFMA fragments (P-scheme order).
// Fragment f = (k*2 + h)*2 + nt; within fragment, lane (q,n), j:
//   B[kdim=q*8+j][col=n] = fcW4[k][uv=h*32+q*8+j][wc=nt*16+n], wc>=28 -> 0
// ---------------------------------------------------------------------------
__global__ __launch_bounds__(256)
void prep_B_kernel(const float* __restrict__ fcW4, unsigned short* __restrict__ Bg)
{
    int i = blockIdx.x * 256 + threadIdx.x;   // [0, 131072)
    int j    = i & 7;
    int lane = (i >> 3) & 63;
    int nt   = (i >> 9) & 1;
    int h    = (i >> 10) & 1;
    int k    = i >> 11;
    int q = lane >> 4, n = lane & 15;
    int uv = h * 32 + q * 8 + j;
    int wc = nt * 16 + n;
    float v;
    if (wc < 16)      v = fcW4[k * 1792 + uv * 16 + wc];
    else if (wc < 24) v = fcW4[k * 1792 + 1024 + uv * 8 + (wc - 16)];
    else if (wc < 28) v = fcW4[k * 1792 + 1536 + uv * 4 + (wc - 24)];
    else              v = 0.0f;
    Bg[i] = f2bf(v);
}

// ---------------------------------------------------------------------------
// Kernel: P-operand MFMA contraction, sorted-edge order, atomic-free.
//   feat[e, wc] = sum_k w3[e,k] * (P[e,:] @ W4[k,:,:])[wc]
// 128 edges/block (4 waves x 32 edges). B double-buffered through LDS in
// 4-k chunks (16 KB) via global_load_lds; w3 staged in LDS [64][128].
// Epilogue: coalesced raw feature-row stores (no atomics).
// ---------------------------------------------------------------------------
__global__ __launch_bounds__(256, 3)
void gemm_kernel(const int* __restrict__ esrc_s,
                 const int* __restrict__ edst_s,
                 const float* __restrict__ Ai,
                 const unsigned short* __restrict__ w3gT,
                 const unsigned short* __restrict__ Bg,
                 float* __restrict__ featbuf)
{
    __shared__ __align__(16) unsigned short w3s[64 * 128];   // 16 KB
    __shared__ __align__(16) unsigned char Bs[2][16384];     // 32 KB

    const int tid  = threadIdx.x;
    const int wave = tid >> 6;
    const int lane = tid & 63;
    const int q    = lane >> 4;
    const int n    = lane & 15;
    const int be0  = blockIdx.x * 128;
    const int ew0  = be0 + wave * 32;

    // stage w3 [64][128] bf16 (256 B per k-row)
#pragma unroll
    for (int it = 0; it < 4; ++it) {
        int idx = it * 256 + tid;            // 16B unit, 0..1023
        int k = idx >> 4, seg = idx & 15;
        const unsigned short* gp = w3gT + (size_t)k * NE + be0 + seg * 8;
        unsigned char* lb = ((unsigned char*)w3s) + (it * 256 + wave * 64) * 16;
        __builtin_amdgcn_global_load_lds(
            (const __attribute__((address_space(1))) unsigned int*)gp,
            (__attribute__((address_space(3))) unsigned int*)lb, 16, 0, 0);
    }

    // B chunk stager: chunk c = k in [4c, 4c+4), 16 KB contiguous in Bg
    auto stageB = [&](int c, int buf) {
#pragma unroll
        for (int it = 0; it < 4; ++it) {
            int idx = it * 256 + tid;
            const unsigned char* gp = ((const unsigned char*)Bg) + c * 16384 + idx * 16;
            unsigned char* lb = Bs[buf] + (it * 256 + wave * 64) * 16;
            __builtin_amdgcn_global_load_lds(
                (const __attribute__((address_space(1))) unsigned int*)gp,
                (__attribute__((address_space(3))) unsigned int*)lb, 16, 0, 0);
        }
    };
    stageB(0, 0);

    // k-invariant P fragments: P[e, uv=h*32+q*8+j] = As[h*4+q]*Ad[j]
    union AF { unsigned int u[4]; short8 s8; };
    AF P[2][2];
#pragma unroll
    for (int t = 0; t < 2; ++t) {
        int e = ew0 + t * 16 + n;
        int s = esrc_s[e], d = edst_s[e];
        float As0 = Ai[s * 8 + q];
        float As1 = Ai[s * 8 + 4 + q];
        float4 d0 = *(const float4*)&Ai[d * 8];
        float4 d1 = *(const float4*)&Ai[d * 8 + 4];
        float Ad[8] = {d0.x, d0.y, d0.z, d0.w, d1.x, d1.y, d1.z, d1.w};
#pragma unroll
        for (int h = 0; h < 2; ++h) {
            float s0 = h ? As1 : As0;
            P[t][h].u[0] = pk_bf16(s0 * Ad[0], s0 * Ad[1]);
            P[t][h].u[1] = pk_bf16(s0 * Ad[2], s0 * Ad[3]);
            P[t][h].u[2] = pk_bf16(s0 * Ad[4], s0 * Ad[5]);
            P[t][h].u[3] = pk_bf16(s0 * Ad[6], s0 * Ad[7]);
        }
    }

    __syncthreads();   // w3 + B chunk 0 staged

    f32x4 out[2][2];
#pragma unroll
    for (int t = 0; t < 2; ++t)
#pragma unroll
        for (int nt = 0; nt < 2; ++nt)
            out[t][nt] = (f32x4){0.f, 0.f, 0.f, 0.f};
    const f32x4 Z4 = (f32x4){0.f, 0.f, 0.f, 0.f};

#pragma unroll 1
    for (int c = 0; c < 16; ++c) {
        int cur = c & 1;
        if (c < 15) stageB(c + 1, cur ^ 1);
#pragma unroll
        for (int kk = 0; kk < 4; ++kk) {
            int k = c * 4 + kk;
            float w3f[2][4];
#pragma unroll
            for (int t = 0; t < 2; ++t) {
                uint2 v = *(const uint2*)&w3s[k * 128 + wave * 32 + t * 16 + q * 4];
                w3f[t][0] = __uint_as_float(v.x << 16);
                w3f[t][1] = __uint_as_float(v.x & 0xFFFF0000u);
                w3f[t][2] = __uint_as_float(v.y << 16);
                w3f[t][3] = __uint_as_float(v.y & 0xFFFF0000u);
            }
            short8 Bf[2][2];
#pragma unroll
            for (int h = 0; h < 2; ++h)
#pragma unroll
                for (int nt = 0; nt < 2; ++nt)
                    Bf[h][nt] = *(const short8*)(Bs[cur] + ((kk * 2 + h) * 2 + nt) * 1024 + lane * 16);
#pragma unroll
            for (int t = 0; t < 2; ++t) {
#pragma unroll
                for (int nt = 0; nt < 2; ++nt) {
                    f32x4 Q = __builtin_amdgcn_mfma_f32_16x16x32_bf16(
                        P[t][0].s8, Bf[0][nt], Z4, 0, 0, 0);
                    Q = __builtin_amdgcn_mfma_f32_16x16x32_bf16(
                        P[t][1].s8, Bf[1][nt], Q, 0, 0, 0);
#pragma unroll
                    for (int r = 0; r < 4; ++r)
                        out[t][nt][r] += w3f[t][r] * Q[r];
                }
            }
        }
        __syncthreads();
    }

    // epilogue: raw 32-wide feature rows, coalesced (C-layout: col=n, row=q*4+r)
#pragma unroll
    for (int t = 0; t < 2; ++t) {
#pragma unroll
        for (int r = 0; r < 4; ++r) {
            int e = ew0 + t * 16 + q * 4 + r;
            featbuf[e * 32 + n]      = out[t][0][r];
            featbuf[e * 32 + 16 + n] = out[t][1][r];
        }
    }
}

// ---------------------------------------------------------------------------
// Kernel: per-node segment mean over contiguous sorted edges + sh expansion.
// 1 wave per node; lane j owns output column j (j<60).
// ---------------------------------------------------------------------------
__global__ __launch_bounds__(64)
void segment_kernel(const int* __restrict__ offsets,
                    const float* __restrict__ featbuf,
                    const float* __restrict__ unit,
                    float* __restrict__ out)
{
    const float s3c  = 1.7320508075688772f;
    const float s5c  = 2.2360679774997896f;
    const float s15c = 3.872983346207417f;

    int nd = blockIdx.x;
    int j  = threadIdx.x;
    int off0 = offsets[nd], off1 = offsets[nd + 1];

    int c = 0, mode = 0, m = 0;
    if (j < 16)      { c = j; mode = 0; }
    else if (j < 40) { int w = (j - 16) / 3; m = (j - 16) % 3; c = 16 + w; mode = 1; }
    else if (j < 60) { int w = (j - 40) / 5; m = (j - 40) % 5; c = 24 + w; mode = 2; }
    else             { c = 0; mode = 3; }

    float sum = 0.f;
    for (int e = off0; e < off1; ++e) {
        float f = featbuf[e * 32 + c];
        float sh = 1.f;
        if (mode == 1 || mode == 2) {
            float ux = unit[e * 3 + 0], uy = unit[e * 3 + 1], uz = unit[e * 3 + 2];
            if (mode == 1) {
                sh = s3c * (m == 0 ? ux : (m == 1 ? uy : uz));
            } else {
                if (m == 0)      sh = s15c * ux * uz;
                else if (m == 1) sh = s15c * ux * uy;
                else if (m == 2) sh = s5c * (uy * uy - 0.5f * (ux * ux + uz * uz));
                else if (m == 3) sh = s15c * uy * uz;
                else             sh = 0.5f * s15c * (uz * uz - ux * ux);
            }
        }
        sum += f * sh;
    }
    if (j < 60) {
        float cnt = (float)(off1 - off0);
        out[nd * 60 + j] = sum * (1.0f / 64.0f) / fmaxf(cnt, 1.0f);
    }
}

extern "C" void kernel_launch(void* const* d_in, const int* in_sizes, int n_in,
                              void* d_out, int out_size, void* d_ws, size_t ws_size,
                              hipStream_t stream)
{
    const float* pos     = (const float*)d_in[0];
    const int*   A       = (const int*)d_in[1];
    const int*   batch   = (const int*)d_in[2];
    const int*   esrc    = (const int*)d_in[3];
    const int*   edst    = (const int*)d_in[4];
    const float* shifts  = (const float*)d_in[5];
    const float* cell    = (const float*)d_in[6];
    const float* emb_tab = (const float*)d_in[7];
    const float* fitW1   = (const float*)d_in[8];
    const float* fitb1   = (const float*)d_in[9];
    const float* fitW2   = (const float*)d_in[10];
    const float* fitb2   = (const float*)d_in[11];
    const float* fitW3   = (const float*)d_in[12];
    const float* fitb3   = (const float*)d_in[13];
    const float* fcW1    = (const float*)d_in[14];
    const float* fcW2    = (const float*)d_in[15];
    const float* fcW3    = (const float*)d_in[16];
    const float* fcW4    = (const float*)d_in[17];

    float* out = (float*)d_out;

    // workspace layout (all 16B-aligned)
    char* W = (char*)d_ws;
    float* Ai      = (float*)W;  W += (size_t)NN * 8 * 4;
    int* sortidx   = (int*)W;    W += (size_t)NE * 4;
    int* esrc_s    = (int*)W;    W += (size_t)NE * 4;
    int* edst_s    = (int*)W;    W += (size_t)NE * 4;
    int* hist      = (int*)W;    W += (size_t)NN * 4;
    int* poscnt    = (int*)W;    W += (size_t)NN * 4;
    int* offsets   = (int*)W;    W += (size_t)(NN + 8) * 4;
    float* unit    = (float*)W;  W += (size_t)NE * 3 * 4;
    unsigned short* w3gT = (unsigned short*)W; W += (size_t)NE * 64 * 2;
    unsigned short* Bg   = (unsigned short*)W; W += (size_t)131072 * 2;
    float* featbuf = (float*)W;  W += (size_t)NE * 32 * 4;

    hipMemsetAsync(hist,   0, (size_t)NN * 4, stream);
    hipMemsetAsync(poscnt, 0, (size_t)NN * 4, stream);

    hist_kernel<<<(NE + 255) / 256, 256, 0, stream>>>(edst, hist);
    scan_kernel<<<1, 256, 0, stream>>>(hist, offsets);
    rank_kernel<<<(NE + 255) / 256, 256, 0, stream>>>(edst, offsets, poscnt, sortidx);

    node_mlp_kernel<<<(NN + 255) / 256, 256, 0, stream>>>(
        A, emb_tab, fitW1, fitb1, fitW2, fitb2, fitW3, fitb3, Ai);

    edge_mlp_kernel<<<NE / 128, 256, 0, stream>>>(
        pos, batch, esrc, edst, shifts, cell, fcW1, fcW2, fcW3,
        sortidx, esrc_s, edst_s, w3gT, unit);

    prep_B_kernel<<<131072 / 256, 256, 0, stream>>>(fcW4, Bg);

    gemm_kernel<<<NE / 128, 256, 0, stream>>>(
        esrc_s, edst_s, Ai, w3gT, Bg, featbuf);

    segment_kernel<<<NN, 64, 0, stream>>>(offsets, featbuf, unit, out);
}

// Round 7
// 250.774 us; speedup vs baseline: 1.5698x; 1.5698x over previous
//
#include <hip/hip_runtime.h>
#include <hip/hip_bf16.h>
#include <math.h>

#define NN 10000
#define NE 131072

typedef __attribute__((ext_vector_type(8))) short short8;
typedef __attribute__((ext_vector_type(4))) float f32x4;

__device__ __forceinline__ float silu_f(float x) {
    return x / (1.0f + __expf(-x));
}

// round-to-nearest-even f32 -> bf16 (finite inputs only)
__device__ __forceinline__ unsigned short f2bf(float f) {
    unsigned int u = __float_as_uint(f);
    u += 0x7FFFu + ((u >> 16) & 1u);
    return (unsigned short)(u >> 16);
}

// packed pair via HW v_cvt_pk_bf16_f32 (x = low half)
__device__ __forceinline__ unsigned int pk_bf16(float lo, float hi) {
    __hip_bfloat162 h = __float22bfloat162_rn(float2{lo, hi});
    return *reinterpret_cast<unsigned int*>(&h);
}

// ---------------------------------------------------------------------------
// Sort machinery: counting sort of edges by dst (10000 bins).
// ---------------------------------------------------------------------------
__global__ __launch_bounds__(256)
void hist_kernel(const int* __restrict__ edst, int* __restrict__ hist)
{
    int e = blockIdx.x * 256 + threadIdx.x;
    if (e < NE) atomicAdd(&hist[edst[e]], 1);
}

__global__ __launch_bounds__(256)
void scan_kernel(const int* __restrict__ hist, int* __restrict__ offsets)
{
    __shared__ int part[256];
    int tid = threadIdx.x;
    int base = tid * 40, s = 0;
    for (int r = 0; r < 40; ++r) {
        int idx = base + r;
        if (idx < NN) s += hist[idx];
    }
    part[tid] = s;
    __syncthreads();
    if (tid == 0) {
        int run = 0;
        for (int i = 0; i < 256; ++i) { int t = part[i]; part[i] = run; run += t; }
        offsets[NN] = run;   // == NE
    }
    __syncthreads();
    int run = part[tid];
    for (int r = 0; r < 40; ++r) {
        int idx = base + r;
        if (idx < NN) { offsets[idx] = run; run += hist[idx]; }
    }
}

__global__ __launch_bounds__(256)
void rank_kernel(const int* __restrict__ edst, const int* __restrict__ offsets,
                 int* __restrict__ poscnt, int* __restrict__ sortidx)
{
    int e = blockIdx.x * 256 + threadIdx.x;
    if (e >= NE) return;
    int d = edst[e];
    int p = offsets[d] + atomicAdd(&poscnt[d], 1);
    sortidx[p] = e;
}

// ---------------------------------------------------------------------------
// Kernel: per-node MLP  embed(16) -> 64 -> 32 -> 8  (Ai)
// ---------------------------------------------------------------------------
__global__ __launch_bounds__(256)
void node_mlp_kernel(const int* __restrict__ A,
                     const float* __restrict__ emb_tab,
                     const float* __restrict__ W1, const float* __restrict__ b1,
                     const float* __restrict__ W2, const float* __restrict__ b2,
                     const float* __restrict__ W3, const float* __restrict__ b3,
                     float* __restrict__ Ai)
{
    int n = blockIdx.x * blockDim.x + threadIdx.x;
    if (n >= NN) return;
    int a = A[n];
    float h[16];
#pragma unroll
    for (int i = 0; i < 16; ++i) h[i] = emb_tab[a * 16 + i];

    float h1[64];
#pragma unroll
    for (int j = 0; j < 64; ++j) h1[j] = b1[j];
#pragma unroll
    for (int i = 0; i < 16; ++i) {
        float hv = h[i];
#pragma unroll
        for (int j = 0; j < 64; ++j) h1[j] += hv * W1[i * 64 + j];
    }
#pragma unroll
    for (int j = 0; j < 64; ++j) h1[j] = silu_f(h1[j]);

    float h2[32];
#pragma unroll
    for (int j = 0; j < 32; ++j) h2[j] = b2[j];
#pragma unroll
    for (int i = 0; i < 64; ++i) {
        float hv = h1[i];
#pragma unroll
        for (int j = 0; j < 32; ++j) h2[j] += hv * W2[i * 32 + j];
    }
#pragma unroll
    for (int j = 0; j < 32; ++j) h2[j] = silu_f(h2[j]);

#pragma unroll
    for (int j = 0; j < 8; ++j) {
        float s = b3[j];
#pragma unroll
        for (int i = 0; i < 32; ++i) s += h2[i] * W3[i * 8 + j];
        Ai[n * 8 + j] = s;
    }
}

// ---------------------------------------------------------------------------
// Kernel: pre-swizzle fc_W1/2/3 into bf16 MFMA B-fragments.
// 20 frags of 512 bf16: L1 frags 0..3 (K=32 padded from 10), L2 4..11,
// L3 12..19 (f = base + kf*4 + nt). Element (lane,j):
//   B[k = kf*32 + (lane>>4)*8 + j][col = nt*16 + (lane&15)]
// ---------------------------------------------------------------------------
__global__ __launch_bounds__(256)
void prep_W_kernel(const float* __restrict__ fcW1,
                   const float* __restrict__ fcW2,
                   const float* __restrict__ fcW3,
                   unsigned short* __restrict__ Wg)
{
    int i = blockIdx.x * 256 + threadIdx.x;   // [0, 10240)
    int j    = i & 7;
    int lane = (i >> 3) & 63;
    int f    = i >> 9;
    int q = lane >> 4, n = lane & 15;
    int L, kf, nt;
    if (f < 4)       { L = 1; kf = 0;            nt = f; }
    else if (f < 12) { L = 2; kf = (f - 4) >> 2; nt = (f - 4) & 3; }
    else             { L = 3; kf = (f - 12) >> 2; nt = (f - 12) & 3; }
    int k = kf * 32 + q * 8 + j;
    int col = nt * 16 + n;
    float v = 0.0f;
    if (L == 1)      { if (k < 10) v = fcW1[k * 64 + col]; }
    else if (L == 2) v = fcW2[k * 64 + col];
    else             v = fcW3[k * 64 + col];
    Wg[i] = f2bf(v);
}

// ---------------------------------------------------------------------------
// Kernel: per-edge geometry + radial MLP via MFMA, sorted order.
// 256 edges/block = 4 waves x 64 edges, each wave independent after the one
// weight-staging barrier. act LDS [64 edges][68] bf16 per wave (pad 68:
// <=4-way conflicts, 8B-aligned b64 A-frag reads). Layers = bf16 MFMA with
// fp32 accum + per-nt silu epilogue (C live-set 16 regs). w3 exits via
// in-LDS transpose to [k][edge] -> 128B-coalesced global stores.
// launch_bounds(256,2): VGPR cap 256, no spill (round-6 lesson: tight caps
// spill to scratch -> 5x WRITE_SIZE).
// ---------------------------------------------------------------------------
__global__ __launch_bounds__(256, 2)
void edge_mlp_kernel(const float* __restrict__ pos,
                     const int* __restrict__ batch,
                     const int* __restrict__ esrc,
                     const int* __restrict__ edst,
                     const float* __restrict__ shifts,
                     const float* __restrict__ cell,
                     const unsigned short* __restrict__ Wg,
                     const int* __restrict__ sortidx,
                     int* __restrict__ esrc_s,
                     int* __restrict__ edst_s,
                     unsigned short* __restrict__ w3gT,
                     float* __restrict__ unit)
{
    __shared__ __align__(16) unsigned short Wbuf[10240];    // 20 KB
    __shared__ __align__(16) unsigned short actb[4][64 * 68]; // 4 x 8.5 KB

    const int tid  = threadIdx.x;
    const int wave = tid >> 6;
    const int lane = tid & 63;
    const int q    = lane >> 4;
    const int n    = lane & 15;
    const int i0   = blockIdx.x * 256 + wave * 64;
    const int i    = i0 + lane;

    // ---- stage weight fragments (block-shared, 1280 x 16B) ----
#pragma unroll
    for (int it = 0; it < 5; ++it) {
        int idx = it * 256 + tid;
        const unsigned short* gp = Wg + idx * 8;
        unsigned short* lb = Wbuf + (it * 256 + wave * 64) * 8;
        __builtin_amdgcn_global_load_lds(
            (const __attribute__((address_space(1))) unsigned int*)gp,
            (__attribute__((address_space(3))) unsigned int*)lb, 16, 0, 0);
    }

    unsigned short* actw = actb[wave];

    // ---- geometry (1 lane = 1 edge) ----
    int e = sortidx[i];
    int s = esrc[e], d = edst[e];
    esrc_s[i] = s;
    edst_s[i] = d;
    int b = batch[s];
    const float* C = cell + b * 9;
    float sx = shifts[e * 3 + 0], sy = shifts[e * 3 + 1], sz = shifts[e * 3 + 2];
    float vx = pos[d * 3 + 0] - pos[s * 3 + 0] + sx * C[0] + sy * C[3] + sz * C[6];
    float vy = pos[d * 3 + 1] - pos[s * 3 + 1] + sx * C[1] + sy * C[4] + sz * C[7];
    float vz = pos[d * 3 + 2] - pos[s * 3 + 2] + sx * C[2] + sy * C[5] + sz * C[8];
    float len = sqrtf(vx * vx + vy * vy + vz * vz);
    float inv = 1.0f / fmaxf(len, 1e-9f);
    unit[i * 3 + 0] = vx * inv;
    unit[i * 3 + 1] = vy * inv;
    unit[i * 3 + 2] = vz * inv;

    // soft_one_hot (sqrt(10) cancels with fc_W1's /sqrt(10))
    float embv[10];
    float base = len * 2.75f;
#pragma unroll
    for (int ii = 0; ii < 10; ++ii) {
        float dd = base - (float)(ii + 1);
        embv[ii] = __expf(-dd * dd) * (1.0f / 1.12f);
    }
    // pack emb -> act row `lane`, k in [0,32) (zero-padded past 10)
    {
        unsigned int u0 = pk_bf16(embv[0], embv[1]);
        unsigned int u1 = pk_bf16(embv[2], embv[3]);
        unsigned int u2 = pk_bf16(embv[4], embv[5]);
        unsigned int u3 = pk_bf16(embv[6], embv[7]);
        unsigned int u4 = pk_bf16(embv[8], embv[9]);
        uint2* arow = (uint2*)&actw[lane * 68];
        arow[0] = uint2{u0, u1};
        arow[1] = uint2{u2, u3};
        arow[2] = uint2{u4, 0u};
        arow[3] = uint2{0u, 0u};
        arow[4] = uint2{0u, 0u};
        arow[5] = uint2{0u, 0u};
        arow[6] = uint2{0u, 0u};
        arow[7] = uint2{0u, 0u};
    }

    __syncthreads();   // weights staged (act is same-wave: DS order suffices)

    union AF { unsigned int u[4]; short8 s8; };
    const f32x4 Z4 = (f32x4){0.f, 0.f, 0.f, 0.f};

    auto loadA = [&](int t, int kf) -> AF {
        const unsigned short* ap = &actw[(t * 16 + n) * 68 + kf * 32 + q * 8];
        uint2 a = *(const uint2*)ap;
        uint2 c = *(const uint2*)(ap + 4);
        AF f; f.u[0] = a.x; f.u[1] = a.y; f.u[2] = c.x; f.u[3] = c.y;
        return f;
    };
    auto loadW = [&](int f) -> short8 {
        return *(const short8*)&Wbuf[(f * 64 + lane) * 8];
    };

    // ---- layer 1: K=32 (padded emb), N=64 ----
    {
        AF A1[4];
#pragma unroll
        for (int t = 0; t < 4; ++t) A1[t] = loadA(t, 0);
#pragma unroll
        for (int nt = 0; nt < 4; ++nt) {
            short8 W0 = loadW(nt);
            f32x4 Cc[4];
#pragma unroll
            for (int t = 0; t < 4; ++t)
                Cc[t] = __builtin_amdgcn_mfma_f32_16x16x32_bf16(A1[t].s8, W0, Z4, 0, 0, 0);
#pragma unroll
            for (int t = 0; t < 4; ++t)
#pragma unroll
                for (int r = 0; r < 4; ++r)
                    actw[(t * 16 + q * 4 + r) * 68 + nt * 16 + n] = f2bf(silu_f(Cc[t][r]));
        }
    }

    // ---- layer 2: K=64 ----
    {
        AF A2[4][2];
#pragma unroll
        for (int t = 0; t < 4; ++t)
#pragma unroll
            for (int kf = 0; kf < 2; ++kf) A2[t][kf] = loadA(t, kf);
#pragma unroll
        for (int nt = 0; nt < 4; ++nt) {
            short8 Wk0 = loadW(4 + nt);
            short8 Wk1 = loadW(8 + nt);
            f32x4 Cc[4];
#pragma unroll
            for (int t = 0; t < 4; ++t) {
                Cc[t] = __builtin_amdgcn_mfma_f32_16x16x32_bf16(A2[t][0].s8, Wk0, Z4, 0, 0, 0);
                Cc[t] = __builtin_amdgcn_mfma_f32_16x16x32_bf16(A2[t][1].s8, Wk1, Cc[t], 0, 0, 0);
            }
#pragma unroll
            for (int t = 0; t < 4; ++t)
#pragma unroll
                for (int r = 0; r < 4; ++r)
                    actw[(t * 16 + q * 4 + r) * 68 + nt * 16 + n] = f2bf(silu_f(Cc[t][r] * 0.125f));
        }
    }

    // ---- layer 3: K=64, epilogue -> transpose buffer [k][edge] (reuse actw) ----
    {
        AF A3[4][2];
#pragma unroll
        for (int t = 0; t < 4; ++t)
#pragma unroll
            for (int kf = 0; kf < 2; ++kf) A3[t][kf] = loadA(t, kf);
#pragma unroll
        for (int nt = 0; nt < 4; ++nt) {
            short8 Wk0 = loadW(12 + nt);
            short8 Wk1 = loadW(16 + nt);
            f32x4 Cc[4];
#pragma unroll
            for (int t = 0; t < 4; ++t) {
                Cc[t] = __builtin_amdgcn_mfma_f32_16x16x32_bf16(A3[t][0].s8, Wk0, Z4, 0, 0, 0);
                Cc[t] = __builtin_amdgcn_mfma_f32_16x16x32_bf16(A3[t][1].s8, Wk1, Cc[t], 0, 0, 0);
            }
            // trans[k = nt*16+n][edge = t*16+q*4+r]
#pragma unroll
            for (int t = 0; t < 4; ++t)
#pragma unroll
                for (int r = 0; r < 4; ++r)
                    actw[(nt * 16 + n) * 68 + t * 16 + q * 4 + r] = f2bf(silu_f(Cc[t][r] * 0.125f));
        }
    }

    // ---- coalesced w3 stores: 4 rows x 128 B per iteration ----
#pragma unroll
    for (int g = 0; g < 16; ++g) {
        int k = g * 4 + q;
        int c4 = n * 4;
        uint2 v = *(const uint2*)&actw[k * 68 + c4];
        *(uint2*)&w3gT[(size_t)k * NE + i0 + c4] = v;
    }
}

// ---------------------------------------------------------------------------
// Kernel: build B = fc_W4 as bf16 MFMA fragments (P-scheme order).
// Fragment f = (k*2 + h)*2 + nt; within fragment, lane (q,n), j:
//   B[kdim=q*8+j][col=n] = fcW4[k][uv=h*32+q*8+j][wc=nt*16+n], wc>=28 -> 0
// ---------------------------------------------------------------------------
__global__ __launch_bounds__(256)
void prep_B_kernel(const float* __restrict__ fcW4, unsigned short* __restrict__ Bg)
{
    int i = blockIdx.x * 256 + threadIdx.x;   // [0, 131072)
    int j    = i & 7;
    int lane = (i >> 3) & 63;
    int nt   = (i >> 9) & 1;
    int h    = (i >> 10) & 1;
    int k    = i >> 11;
    int q = lane >> 4, n = lane & 15;
    int uv = h * 32 + q * 8 + j;
    int wc = nt * 16 + n;
    float v;
    if (wc < 16)      v = fcW4[k * 1792 + uv * 16 + wc];
    else if (wc < 24) v = fcW4[k * 1792 + 1024 + uv * 8 + (wc - 16)];
    else if (wc < 28) v = fcW4[k * 1792 + 1536 + uv * 4 + (wc - 24)];
    else              v = 0.0f;
    Bg[i] = f2bf(v);
}

// ---------------------------------------------------------------------------
// Kernel: P-operand MFMA contraction, sorted-edge order, atomic-free.
//   feat[e, wc] = sum_k w3[e,k] * (P[e,:] @ W4[k,:,:])[wc]
// 128 edges/block (4 waves x 32 edges). B double-buffered through LDS in
// 4-k chunks (16 KB) via global_load_lds; w3 staged in LDS [64][128].
// Epilogue: coalesced raw feature-row stores (no atomics).
// ---------------------------------------------------------------------------
__global__ __launch_bounds__(256, 3)
void gemm_kernel(const int* __restrict__ esrc_s,
                 const int* __restrict__ edst_s,
                 const float* __restrict__ Ai,
                 const unsigned short* __restrict__ w3gT,
                 const unsigned short* __restrict__ Bg,
                 float* __restrict__ featbuf)
{
    __shared__ __align__(16) unsigned short w3s[64 * 128];   // 16 KB
    __shared__ __align__(16) unsigned char Bs[2][16384];     // 32 KB

    const int tid  = threadIdx.x;
    const int wave = tid >> 6;
    const int lane = tid & 63;
    const int q    = lane >> 4;
    const int n    = lane & 15;
    const int be0  = blockIdx.x * 128;
    const int ew0  = be0 + wave * 32;

    // stage w3 [64][128] bf16 (256 B per k-row)
#pragma unroll
    for (int it = 0; it < 4; ++it) {
        int idx = it * 256 + tid;            // 16B unit, 0..1023
        int k = idx >> 4, seg = idx & 15;
        const unsigned short* gp = w3gT + (size_t)k * NE + be0 + seg * 8;
        unsigned char* lb = ((unsigned char*)w3s) + (it * 256 + wave * 64) * 16;
        __builtin_amdgcn_global_load_lds(
            (const __attribute__((address_space(1))) unsigned int*)gp,
            (__attribute__((address_space(3))) unsigned int*)lb, 16, 0, 0);
    }

    // B chunk stager: chunk c = k in [4c, 4c+4), 16 KB contiguous in Bg
    auto stageB = [&](int c, int buf) {
#pragma unroll
        for (int it = 0; it < 4; ++it) {
            int idx = it * 256 + tid;
            const unsigned char* gp = ((const unsigned char*)Bg) + c * 16384 + idx * 16;
            unsigned char* lb = Bs[buf] + (it * 256 + wave * 64) * 16;
            __builtin_amdgcn_global_load_lds(
                (const __attribute__((address_space(1))) unsigned int*)gp,
                (__attribute__((address_space(3))) unsigned int*)lb, 16, 0, 0);
        }
    };
    stageB(0, 0);

    // k-invariant P fragments: P[e, uv=h*32+q*8+j] = As[h*4+q]*Ad[j]
    union AF { unsigned int u[4]; short8 s8; };
    AF P[2][2];
#pragma unroll
    for (int t = 0; t < 2; ++t) {
        int e = ew0 + t * 16 + n;
        int s = esrc_s[e], d = edst_s[e];
        float As0 = Ai[s * 8 + q];
        float As1 = Ai[s * 8 + 4 + q];
        float4 d0 = *(const float4*)&Ai[d * 8];
        float4 d1 = *(const float4*)&Ai[d * 8 + 4];
        float Ad[8] = {d0.x, d0.y, d0.z, d0.w, d1.x, d1.y, d1.z, d1.w};
#pragma unroll
        for (int h = 0; h < 2; ++h) {
            float s0 = h ? As1 : As0;
            P[t][h].u[0] = pk_bf16(s0 * Ad[0], s0 * Ad[1]);
            P[t][h].u[1] = pk_bf16(s0 * Ad[2], s0 * Ad[3]);
            P[t][h].u[2] = pk_bf16(s0 * Ad[4], s0 * Ad[5]);
            P[t][h].u[3] = pk_bf16(s0 * Ad[6], s0 * Ad[7]);
        }
    }

    __syncthreads();   // w3 + B chunk 0 staged

    f32x4 out[2][2];
#pragma unroll
    for (int t = 0; t < 2; ++t)
#pragma unroll
        for (int nt = 0; nt < 2; ++nt)
            out[t][nt] = (f32x4){0.f, 0.f, 0.f, 0.f};
    const f32x4 Z4 = (f32x4){0.f, 0.f, 0.f, 0.f};

#pragma unroll 1
    for (int c = 0; c < 16; ++c) {
        int cur = c & 1;
        if (c < 15) stageB(c + 1, cur ^ 1);
#pragma unroll
        for (int kk = 0; kk < 4; ++kk) {
            int k = c * 4 + kk;
            float w3f[2][4];
#pragma unroll
            for (int t = 0; t < 2; ++t) {
                uint2 v = *(const uint2*)&w3s[k * 128 + wave * 32 + t * 16 + q * 4];
                w3f[t][0] = __uint_as_float(v.x << 16);
                w3f[t][1] = __uint_as_float(v.x & 0xFFFF0000u);
                w3f[t][2] = __uint_as_float(v.y << 16);
                w3f[t][3] = __uint_as_float(v.y & 0xFFFF0000u);
            }
            short8 Bf[2][2];
#pragma unroll
            for (int h = 0; h < 2; ++h)
#pragma unroll
                for (int nt = 0; nt < 2; ++nt)
                    Bf[h][nt] = *(const short8*)(Bs[cur] + ((kk * 2 + h) * 2 + nt) * 1024 + lane * 16);
#pragma unroll
            for (int t = 0; t < 2; ++t) {
#pragma unroll
                for (int nt = 0; nt < 2; ++nt) {
                    f32x4 Q = __builtin_amdgcn_mfma_f32_16x16x32_bf16(
                        P[t][0].s8, Bf[0][nt], Z4, 0, 0, 0);
                    Q = __builtin_amdgcn_mfma_f32_16x16x32_bf16(
                        P[t][1].s8, Bf[1][nt], Q, 0, 0, 0);
#pragma unroll
                    for (int r = 0; r < 4; ++r)
                        out[t][nt][r] += w3f[t][r] * Q[r];
                }
            }
        }
        __syncthreads();
    }

    // epilogue: raw 32-wide feature rows, coalesced (C-layout: col=n, row=q*4+r)
#pragma unroll
    for (int t = 0; t < 2; ++t) {
#pragma unroll
        for (int r = 0; r < 4; ++r) {
            int e = ew0 + t * 16 + q * 4 + r;
            featbuf[e * 32 + n]      = out[t][0][r];
            featbuf[e * 32 + 16 + n] = out[t][1][r];
        }
    }
}

// ---------------------------------------------------------------------------
// Kernel: per-node segment mean over contiguous sorted edges + sh expansion.
// 1 wave per node; lane j owns output column j (j<60).
// ---------------------------------------------------------------------------
__global__ __launch_bounds__(64)
void segment_kernel(const int* __restrict__ offsets,
                    const float* __restrict__ featbuf,
                    const float* __restrict__ unit,
                    float* __restrict__ out)
{
    const float s3c  = 1.7320508075688772f;
    const float s5c  = 2.2360679774997896f;
    const float s15c = 3.872983346207417f;

    int nd = blockIdx.x;
    int j  = threadIdx.x;
    int off0 = offsets[nd], off1 = offsets[nd + 1];

    int c = 0, mode = 0, m = 0;
    if (j < 16)      { c = j; mode = 0; }
    else if (j < 40) { int w = (j - 16) / 3; m = (j - 16) % 3; c = 16 + w; mode = 1; }
    else if (j < 60) { int w = (j - 40) / 5; m = (j - 40) % 5; c = 24 + w; mode = 2; }
    else             { c = 0; mode = 3; }

    float sum = 0.f;
    for (int e = off0; e < off1; ++e) {
        float f = featbuf[e * 32 + c];
        float sh = 1.f;
        if (mode == 1 || mode == 2) {
            float ux = unit[e * 3 + 0], uy = unit[e * 3 + 1], uz = unit[e * 3 + 2];
            if (mode == 1) {
                sh = s3c * (m == 0 ? ux : (m == 1 ? uy : uz));
            } else {
                if (m == 0)      sh = s15c * ux * uz;
                else if (m == 1) sh = s15c * ux * uy;
                else if (m == 2) sh = s5c * (uy * uy - 0.5f * (ux * ux + uz * uz));
                else if (m == 3) sh = s15c * uy * uz;
                else             sh = 0.5f * s15c * (uz * uz - ux * ux);
            }
        }
        sum += f * sh;
    }
    if (j < 60) {
        float cnt = (float)(off1 - off0);
        out[nd * 60 + j] = sum * (1.0f / 64.0f) / fmaxf(cnt, 1.0f);
    }
}

extern "C" void kernel_launch(void* const* d_in, const int* in_sizes, int n_in,
                              void* d_out, int out_size, void* d_ws, size_t ws_size,
                              hipStream_t stream)
{
    const float* pos     = (const float*)d_in[0];
    const int*   A       = (const int*)d_in[1];
    const int*   batch   = (const int*)d_in[2];
    const int*   esrc    = (const int*)d_in[3];
    const int*   edst    = (const int*)d_in[4];
    const float* shifts  = (const float*)d_in[5];
    const float* cell    = (const float*)d_in[6];
    const float* emb_tab = (const float*)d_in[7];
    const float* fitW1   = (const float*)d_in[8];
    const float* fitb1   = (const float*)d_in[9];
    const float* fitW2   = (const float*)d_in[10];
    const float* fitb2   = (const float*)d_in[11];
    const float* fitW3   = (const float*)d_in[12];
    const float* fitb3   = (const float*)d_in[13];
    const float* fcW1    = (const float*)d_in[14];
    const float* fcW2    = (const float*)d_in[15];
    const float* fcW3    = (const float*)d_in[16];
    const float* fcW4    = (const float*)d_in[17];

    float* out = (float*)d_out;

    // workspace layout (all 16B-aligned)
    char* W = (char*)d_ws;
    float* Ai      = (float*)W;  W += (size_t)NN * 8 * 4;
    int* sortidx   = (int*)W;    W += (size_t)NE * 4;
    int* esrc_s    = (int*)W;    W += (size_t)NE * 4;
    int* edst_s    = (int*)W;    W += (size_t)NE * 4;
    int* hist      = (int*)W;    W += (size_t)NN * 4;
    int* poscnt    = (int*)W;    W += (size_t)NN * 4;
    int* offsets   = (int*)W;    W += (size_t)(NN + 8) * 4;
    float* unit    = (float*)W;  W += (size_t)NE * 3 * 4;
    unsigned short* w3gT = (unsigned short*)W; W += (size_t)NE * 64 * 2;
    unsigned short* Bg   = (unsigned short*)W; W += (size_t)131072 * 2;
    unsigned short* Wg   = (unsigned short*)W; W += (size_t)10240 * 2;
    float* featbuf = (float*)W;  W += (size_t)NE * 32 * 4;

    hipMemsetAsync(hist,   0, (size_t)NN * 4, stream);
    hipMemsetAsync(poscnt, 0, (size_t)NN * 4, stream);

    hist_kernel<<<(NE + 255) / 256, 256, 0, stream>>>(edst, hist);
    scan_kernel<<<1, 256, 0, stream>>>(hist, offsets);
    rank_kernel<<<(NE + 255) / 256, 256, 0, stream>>>(edst, offsets, poscnt, sortidx);

    node_mlp_kernel<<<(NN + 255) / 256, 256, 0, stream>>>(
        A, emb_tab, fitW1, fitb1, fitW2, fitb2, fitW3, fitb3, Ai);

    prep_W_kernel<<<10240 / 256, 256, 0, stream>>>(fcW1, fcW2, fcW3, Wg);
    prep_B_kernel<<<131072 / 256, 256, 0, stream>>>(fcW4, Bg);

    edge_mlp_kernel<<<NE / 256, 256, 0, stream>>>(
        pos, batch, esrc, edst, shifts, cell, Wg,
        sortidx, esrc_s, edst_s, w3gT, unit);

    gemm_kernel<<<NE / 128, 256, 0, stream>>>(
        esrc_s, edst_s, Ai, w3gT, Bg, featbuf);

    segment_kernel<<<NN, 64, 0, stream>>>(offsets, featbuf, unit, out);
}

// Round 8
// 241.776 us; speedup vs baseline: 1.6282x; 1.0372x over previous
//
#include <hip/hip_runtime.h>
#include <hip/hip_bf16.h>
#include <math.h>

#define NN 10000
#define NE 131072

typedef __attribute__((ext_vector_type(8))) short short8;
typedef __attribute__((ext_vector_type(4))) float f32x4;

__device__ __forceinline__ float silu_f(float x) {
    return x / (1.0f + __expf(-x));
}

// round-to-nearest-even f32 -> bf16 (finite inputs only)
__device__ __forceinline__ unsigned short f2bf(float f) {
    unsigned int u = __float_as_uint(f);
    u += 0x7FFFu + ((u >> 16) & 1u);
    return (unsigned short)(u >> 16);
}

// packed pair via HW v_cvt_pk_bf16_f32 (x = low half)
__device__ __forceinline__ unsigned int pk_bf16(float lo, float hi) {
    __hip_bfloat162 h = __float22bfloat162_rn(float2{lo, hi});
    return *reinterpret_cast<unsigned int*>(&h);
}

// ---------------------------------------------------------------------------
// Sort machinery: counting sort of edges by dst (10000 bins).
// ---------------------------------------------------------------------------
__global__ __launch_bounds__(256)
void hist_kernel(const int* __restrict__ edst, int* __restrict__ hist)
{
    int e = blockIdx.x * 256 + threadIdx.x;
    if (e < NE) atomicAdd(&hist[edst[e]], 1);
}

__global__ __launch_bounds__(256)
void scan_kernel(const int* __restrict__ hist, int* __restrict__ offsets)
{
    __shared__ int part[256];
    int tid = threadIdx.x;
    int base = tid * 40, s = 0;
    for (int r = 0; r < 40; ++r) {
        int idx = base + r;
        if (idx < NN) s += hist[idx];
    }
    part[tid] = s;
    __syncthreads();
    if (tid == 0) {
        int run = 0;
        for (int i = 0; i < 256; ++i) { int t = part[i]; part[i] = run; run += t; }
        offsets[NN] = run;   // == NE
    }
    __syncthreads();
    int run = part[tid];
    for (int r = 0; r < 40; ++r) {
        int idx = base + r;
        if (idx < NN) { offsets[idx] = run; run += hist[idx]; }
    }
}

__global__ __launch_bounds__(256)
void rank_kernel(const int* __restrict__ edst, const int* __restrict__ offsets,
                 int* __restrict__ poscnt, int* __restrict__ sortidx)
{
    int e = blockIdx.x * 256 + threadIdx.x;
    if (e >= NE) return;
    int d = edst[e];
    int p = offsets[d] + atomicAdd(&poscnt[d], 1);
    sortidx[p] = e;
}

// ---------------------------------------------------------------------------
// Kernel: per-node MLP  embed(16) -> 64 -> 32 -> 8  (Ai)
// ---------------------------------------------------------------------------
__global__ __launch_bounds__(256)
void node_mlp_kernel(const int* __restrict__ A,
                     const float* __restrict__ emb_tab,
                     const float* __restrict__ W1, const float* __restrict__ b1,
                     const float* __restrict__ W2, const float* __restrict__ b2,
                     const float* __restrict__ W3, const float* __restrict__ b3,
                     float* __restrict__ Ai)
{
    int n = blockIdx.x * blockDim.x + threadIdx.x;
    if (n >= NN) return;
    int a = A[n];
    float h[16];
#pragma unroll
    for (int i = 0; i < 16; ++i) h[i] = emb_tab[a * 16 + i];

    float h1[64];
#pragma unroll
    for (int j = 0; j < 64; ++j) h1[j] = b1[j];
#pragma unroll
    for (int i = 0; i < 16; ++i) {
        float hv = h[i];
#pragma unroll
        for (int j = 0; j < 64; ++j) h1[j] += hv * W1[i * 64 + j];
    }
#pragma unroll
    for (int j = 0; j < 64; ++j) h1[j] = silu_f(h1[j]);

    float h2[32];
#pragma unroll
    for (int j = 0; j < 32; ++j) h2[j] = b2[j];
#pragma unroll
    for (int i = 0; i < 64; ++i) {
        float hv = h1[i];
#pragma unroll
        for (int j = 0; j < 32; ++j) h2[j] += hv * W2[i * 32 + j];
    }
#pragma unroll
    for (int j = 0; j < 32; ++j) h2[j] = silu_f(h2[j]);

#pragma unroll
    for (int j = 0; j < 8; ++j) {
        float s = b3[j];
#pragma unroll
        for (int i = 0; i < 32; ++i) s += h2[i] * W3[i * 8 + j];
        Ai[n * 8 + j] = s;
    }
}

// ---------------------------------------------------------------------------
// Kernel: pre-swizzle fc_W1/2/3 into bf16 MFMA B-fragments.
// 20 frags of 512 bf16: L1 frags 0..3 (K=32 padded from 10), L2 4..11,
// L3 12..19 (f = base + kf*4 + nt). Element (lane,j):
//   B[k = kf*32 + (lane>>4)*8 + j][col = nt*16 + (lane&15)]
// ---------------------------------------------------------------------------
__global__ __launch_bounds__(256)
void prep_W_kernel(const float* __restrict__ fcW1,
                   const float* __restrict__ fcW2,
                   const float* __restrict__ fcW3,
                   unsigned short* __restrict__ Wg)
{
    int i = blockIdx.x * 256 + threadIdx.x;   // [0, 10240)
    int j    = i & 7;
    int lane = (i >> 3) & 63;
    int f    = i >> 9;
    int q = lane >> 4, n = lane & 15;
    int L, kf, nt;
    if (f < 4)       { L = 1; kf = 0;            nt = f; }
    else if (f < 12) { L = 2; kf = (f - 4) >> 2; nt = (f - 4) & 3; }
    else             { L = 3; kf = (f - 12) >> 2; nt = (f - 12) & 3; }
    int k = kf * 32 + q * 8 + j;
    int col = nt * 16 + n;
    float v = 0.0f;
    if (L == 1)      { if (k < 10) v = fcW1[k * 64 + col]; }
    else if (L == 2) v = fcW2[k * 64 + col];
    else             v = fcW3[k * 64 + col];
    Wg[i] = f2bf(v);
}

// ---------------------------------------------------------------------------
// Kernel: build B = fc_W4 as bf16 MFMA fragments (P-scheme order).
// Fragment f = (k*2 + h)*2 + nt; within fragment, lane (q,n), j:
//   B[kdim=q*8+j][col=n] = fcW4[k][uv=h*32+q*8+j][wc=nt*16+n], wc>=28 -> 0
// ---------------------------------------------------------------------------
__global__ __launch_bounds__(256)
void prep_B_kernel(const float* __restrict__ fcW4, unsigned short* __restrict__ Bg)
{
    int i = blockIdx.x * 256 + threadIdx.x;   // [0, 131072)
    int j    = i & 7;
    int lane = (i >> 3) & 63;
    int nt   = (i >> 9) & 1;
    int h    = (i >> 10) & 1;
    int k    = i >> 11;
    int q = lane >> 4, n = lane & 15;
    int uv = h * 32 + q * 8 + j;
    int wc = nt * 16 + n;
    float v;
    if (wc < 16)      v = fcW4[k * 1792 + uv * 16 + wc];
    else if (wc < 24) v = fcW4[k * 1792 + 1024 + uv * 8 + (wc - 16)];
    else if (wc < 28) v = fcW4[k * 1792 + 1536 + uv * 4 + (wc - 24)];
    else              v = 0.0f;
    Bg[i] = f2bf(v);
}

// ---------------------------------------------------------------------------
// FUSED kernel: geometry + radial MLP (MFMA) + P-operand contraction.
// 512 blocks x 256 thr = 4 waves x 64 edges (sorted order), each wave owns
// its 64 edges end-to-end. w3 never leaves LDS: layer-3 epilogue transposes
// it to [k][edge] in the per-wave act buffer, and the k-loop reads it there.
// B (fc_W4 frags) double-buffered via global_load_lds in 8 KB (2-k) chunks.
// LDS: act 4x8.5KB + (B dbuf 16KB  union  Wbuf 20KB) + sd 2KB = 57.3 KB
// -> 2 blocks/CU. launch_bounds(256,2): VGPR cap 256, no spill (r6 lesson).
// Epilogue: coalesced raw feature-row stores (no atomics).
// ---------------------------------------------------------------------------
__global__ __launch_bounds__(256, 2)
void edge_fused_kernel(const float* __restrict__ pos,
                       const int* __restrict__ batch,
                       const int* __restrict__ esrc,
                       const int* __restrict__ edst,
                       const float* __restrict__ shifts,
                       const float* __restrict__ cell,
                       const unsigned short* __restrict__ Wg,
                       const unsigned short* __restrict__ Bg,
                       const int* __restrict__ sortidx,
                       const float* __restrict__ Ai,
                       unsigned short* __restrict__ w3_unused,
                       float* __restrict__ unit,
                       float* __restrict__ featbuf)
{
    __shared__ __align__(16) unsigned char  WBs[20480];       // Wbuf(20KB) U Bs[2][8KB]
    __shared__ __align__(16) unsigned short actb[4][64 * 68]; // 4 x 8.5 KB
    __shared__ int sdbuf[512];                                // [edge][2] = s,d

    const int tid  = threadIdx.x;
    const int wave = tid >> 6;
    const int lane = tid & 63;
    const int q    = lane >> 4;
    const int n    = lane & 15;
    const int i0   = blockIdx.x * 256 + wave * 64;
    const int i    = i0 + lane;

    // ---- stage weight fragments (block-shared, 1280 x 16B) ----
#pragma unroll
    for (int it = 0; it < 5; ++it) {
        int idx = it * 256 + tid;
        const unsigned short* gp = Wg + idx * 8;
        unsigned char* lb = WBs + (it * 256 + wave * 64) * 16;
        __builtin_amdgcn_global_load_lds(
            (const __attribute__((address_space(1))) unsigned int*)gp,
            (__attribute__((address_space(3))) unsigned int*)lb, 16, 0, 0);
    }

    unsigned short* actw = actb[wave];

    // ---- geometry (1 lane = 1 edge) ----
    int e = sortidx[i];
    int s = esrc[e], d = edst[e];
    sdbuf[2 * (wave * 64 + lane)]     = s;
    sdbuf[2 * (wave * 64 + lane) + 1] = d;
    int b = batch[s];
    const float* C = cell + b * 9;
    float sx = shifts[e * 3 + 0], sy = shifts[e * 3 + 1], sz = shifts[e * 3 + 2];
    float vx = pos[d * 3 + 0] - pos[s * 3 + 0] + sx * C[0] + sy * C[3] + sz * C[6];
    float vy = pos[d * 3 + 1] - pos[s * 3 + 1] + sx * C[1] + sy * C[4] + sz * C[7];
    float vz = pos[d * 3 + 2] - pos[s * 3 + 2] + sx * C[2] + sy * C[5] + sz * C[8];
    float len = sqrtf(vx * vx + vy * vy + vz * vz);
    float inv = 1.0f / fmaxf(len, 1e-9f);
    unit[i * 3 + 0] = vx * inv;
    unit[i * 3 + 1] = vy * inv;
    unit[i * 3 + 2] = vz * inv;

    // soft_one_hot (sqrt(10) cancels with fc_W1's /sqrt(10))
    float embv[10];
    float base = len * 2.75f;
#pragma unroll
    for (int ii = 0; ii < 10; ++ii) {
        float dd = base - (float)(ii + 1);
        embv[ii] = __expf(-dd * dd) * (1.0f / 1.12f);
    }
    // pack emb -> act row `lane`, k in [0,32) (zero-padded past 10)
    {
        unsigned int u0 = pk_bf16(embv[0], embv[1]);
        unsigned int u1 = pk_bf16(embv[2], embv[3]);
        unsigned int u2 = pk_bf16(embv[4], embv[5]);
        unsigned int u3 = pk_bf16(embv[6], embv[7]);
        unsigned int u4 = pk_bf16(embv[8], embv[9]);
        uint2* arow = (uint2*)&actw[lane * 68];
        arow[0] = uint2{u0, u1};
        arow[1] = uint2{u2, u3};
        arow[2] = uint2{u4, 0u};
        arow[3] = uint2{0u, 0u};
        arow[4] = uint2{0u, 0u};
        arow[5] = uint2{0u, 0u};
        arow[6] = uint2{0u, 0u};
        arow[7] = uint2{0u, 0u};
    }

    __syncthreads();   // weights staged; sd written

    union AF { unsigned int u[4]; short8 s8; };
    const f32x4 Z4 = (f32x4){0.f, 0.f, 0.f, 0.f};
    const unsigned short* Wbuf = (const unsigned short*)WBs;

    auto loadA = [&](int t, int kf) -> AF {
        const unsigned short* ap = &actw[(t * 16 + n) * 68 + kf * 32 + q * 8];
        uint2 a = *(const uint2*)ap;
        uint2 c = *(const uint2*)(ap + 4);
        AF f; f.u[0] = a.x; f.u[1] = a.y; f.u[2] = c.x; f.u[3] = c.y;
        return f;
    };
    auto loadW = [&](int f) -> short8 {
        return *(const short8*)&Wbuf[(f * 64 + lane) * 8];
    };

    // ---- layer 1: K=32 (padded emb), N=64 ----
    {
        AF A1[4];
#pragma unroll
        for (int t = 0; t < 4; ++t) A1[t] = loadA(t, 0);
#pragma unroll
        for (int nt = 0; nt < 4; ++nt) {
            short8 W0 = loadW(nt);
            f32x4 Cc[4];
#pragma unroll
            for (int t = 0; t < 4; ++t)
                Cc[t] = __builtin_amdgcn_mfma_f32_16x16x32_bf16(A1[t].s8, W0, Z4, 0, 0, 0);
#pragma unroll
            for (int t = 0; t < 4; ++t)
#pragma unroll
                for (int r = 0; r < 4; ++r)
                    actw[(t * 16 + q * 4 + r) * 68 + nt * 16 + n] = f2bf(silu_f(Cc[t][r]));
        }
    }

    // ---- layer 2: K=64 ----
    {
        AF A2[4][2];
#pragma unroll
        for (int t = 0; t < 4; ++t)
#pragma unroll
            for (int kf = 0; kf < 2; ++kf) A2[t][kf] = loadA(t, kf);
#pragma unroll
        for (int nt = 0; nt < 4; ++nt) {
            short8 Wk0 = loadW(4 + nt);
            short8 Wk1 = loadW(8 + nt);
            f32x4 Cc[4];
#pragma unroll
            for (int t = 0; t < 4; ++t) {
                Cc[t] = __builtin_amdgcn_mfma_f32_16x16x32_bf16(A2[t][0].s8, Wk0, Z4, 0, 0, 0);
                Cc[t] = __builtin_amdgcn_mfma_f32_16x16x32_bf16(A2[t][1].s8, Wk1, Cc[t], 0, 0, 0);
            }
#pragma unroll
            for (int t = 0; t < 4; ++t)
#pragma unroll
                for (int r = 0; r < 4; ++r)
                    actw[(t * 16 + q * 4 + r) * 68 + nt * 16 + n] = f2bf(silu_f(Cc[t][r] * 0.125f));
        }
    }

    // ---- layer 3: K=64, epilogue -> w3 transposed [k][edge] in actw ----
    {
        AF A3[4][2];
#pragma unroll
        for (int t = 0; t < 4; ++t)
#pragma unroll
            for (int kf = 0; kf < 2; ++kf) A3[t][kf] = loadA(t, kf);
#pragma unroll
        for (int nt = 0; nt < 4; ++nt) {
            short8 Wk0 = loadW(12 + nt);
            short8 Wk1 = loadW(16 + nt);
            f32x4 Cc[4];
#pragma unroll
            for (int t = 0; t < 4; ++t) {
                Cc[t] = __builtin_amdgcn_mfma_f32_16x16x32_bf16(A3[t][0].s8, Wk0, Z4, 0, 0, 0);
                Cc[t] = __builtin_amdgcn_mfma_f32_16x16x32_bf16(A3[t][1].s8, Wk1, Cc[t], 0, 0, 0);
            }
#pragma unroll
            for (int t = 0; t < 4; ++t)
#pragma unroll
                for (int r = 0; r < 4; ++r)
                    actw[(nt * 16 + n) * 68 + t * 16 + q * 4 + r] = f2bf(silu_f(Cc[t][r] * 0.125f));
        }
    }

    __syncthreads();   // all waves done with Wbuf -> WBs reusable as B dbuf

    // B chunk stager: chunk c covers k in {2c, 2c+1}: 8 frags, 8 KB
    auto stageB = [&](int c, int buf) {
#pragma unroll
        for (int it = 0; it < 2; ++it) {
            int idx = it * 256 + tid;
            const unsigned char* gp = ((const unsigned char*)Bg) + c * 8192 + idx * 16;
            unsigned char* lb = WBs + buf * 8192 + (it * 256 + wave * 64) * 16;
            __builtin_amdgcn_global_load_lds(
                (const __attribute__((address_space(1))) unsigned int*)gp,
                (__attribute__((address_space(3))) unsigned int*)lb, 16, 0, 0);
        }
    };
    stageB(0, 0);

    // k-invariant P fragments (overlaps chunk-0 staging):
    // P[e, uv=h*32+q*8+j] = As[h*4+q]*Ad[j]
    AF P[4][2];
#pragma unroll
    for (int t = 0; t < 4; ++t) {
        int eL = wave * 64 + t * 16 + n;
        int ss = sdbuf[2 * eL];
        int dd = sdbuf[2 * eL + 1];
        float As0 = Ai[ss * 8 + q];
        float As1 = Ai[ss * 8 + 4 + q];
        float4 d0 = *(const float4*)&Ai[dd * 8];
        float4 d1 = *(const float4*)&Ai[dd * 8 + 4];
        float Ad[8] = {d0.x, d0.y, d0.z, d0.w, d1.x, d1.y, d1.z, d1.w};
#pragma unroll
        for (int h = 0; h < 2; ++h) {
            float s0 = h ? As1 : As0;
            P[t][h].u[0] = pk_bf16(s0 * Ad[0], s0 * Ad[1]);
            P[t][h].u[1] = pk_bf16(s0 * Ad[2], s0 * Ad[3]);
            P[t][h].u[2] = pk_bf16(s0 * Ad[4], s0 * Ad[5]);
            P[t][h].u[3] = pk_bf16(s0 * Ad[6], s0 * Ad[7]);
        }
    }

    f32x4 out[4][2];
#pragma unroll
    for (int t = 0; t < 4; ++t)
#pragma unroll
        for (int nt = 0; nt < 2; ++nt)
            out[t][nt] = (f32x4){0.f, 0.f, 0.f, 0.f};

    __syncthreads();   // chunk 0 resident (barrier drains vmcnt)

#pragma unroll 1
    for (int c = 0; c < 32; ++c) {
        int cur = c & 1;
        if (c < 31) stageB(c + 1, cur ^ 1);
#pragma unroll
        for (int kk = 0; kk < 2; ++kk) {
            int k = c * 2 + kk;
            short8 Bf[2][2];
#pragma unroll
            for (int h = 0; h < 2; ++h)
#pragma unroll
                for (int nt = 0; nt < 2; ++nt)
                    Bf[h][nt] = *(const short8*)(WBs + cur * 8192 +
                                 ((kk * 2 + h) * 2 + nt) * 1024 + lane * 16);
#pragma unroll
            for (int t = 0; t < 4; ++t) {
                uint2 v = *(const uint2*)&actw[k * 68 + t * 16 + q * 4];
                float w0 = __uint_as_float(v.x << 16);
                float w1 = __uint_as_float(v.x & 0xFFFF0000u);
                float w2 = __uint_as_float(v.y << 16);
                float w3 = __uint_as_float(v.y & 0xFFFF0000u);
#pragma unroll
                for (int nt = 0; nt < 2; ++nt) {
                    f32x4 Q = __builtin_amdgcn_mfma_f32_16x16x32_bf16(
                        P[t][0].s8, Bf[0][nt], Z4, 0, 0, 0);
                    Q = __builtin_amdgcn_mfma_f32_16x16x32_bf16(
                        P[t][1].s8, Bf[1][nt], Q, 0, 0, 0);
                    out[t][nt][0] += w0 * Q[0];
                    out[t][nt][1] += w1 * Q[1];
                    out[t][nt][2] += w2 * Q[2];
                    out[t][nt][3] += w3 * Q[3];
                }
            }
        }
        __syncthreads();
    }

    // epilogue: raw 32-wide feature rows, coalesced (C-layout: col=n, row=q*4+r)
#pragma unroll
    for (int t = 0; t < 4; ++t) {
#pragma unroll
        for (int r = 0; r < 4; ++r) {
            int eg = i0 + t * 16 + q * 4 + r;
            featbuf[eg * 32 + n]      = out[t][0][r];
            featbuf[eg * 32 + 16 + n] = out[t][1][r];
        }
    }
}

// ---------------------------------------------------------------------------
// Kernel: per-node segment mean over contiguous sorted edges + sh expansion.
// 1 wave per node; lane j owns output column j (j<60). 2-way unrolled
// partial sums (independent chains).
// ---------------------------------------------------------------------------
__global__ __launch_bounds__(64)
void segment_kernel(const int* __restrict__ offsets,
                    const float* __restrict__ featbuf,
                    const float* __restrict__ unit,
                    float* __restrict__ out)
{
    const float s3c  = 1.7320508075688772f;
    const float s5c  = 2.2360679774997896f;
    const float s15c = 3.872983346207417f;

    int nd = blockIdx.x;
    int j  = threadIdx.x;
    int off0 = offsets[nd], off1 = offsets[nd + 1];

    int c = 0, mode = 0, m = 0;
    if (j < 16)      { c = j; mode = 0; }
    else if (j < 40) { int w = (j - 16) / 3; m = (j - 16) % 3; c = 16 + w; mode = 1; }
    else if (j < 60) { int w = (j - 40) / 5; m = (j - 40) % 5; c = 24 + w; mode = 2; }
    else             { c = 0; mode = 3; }

    auto term = [&](int e) -> float {
        float f = featbuf[e * 32 + c];
        float sh = 1.f;
        if (mode == 1 || mode == 2) {
            float ux = unit[e * 3 + 0], uy = unit[e * 3 + 1], uz = unit[e * 3 + 2];
            if (mode == 1) {
                sh = s3c * (m == 0 ? ux : (m == 1 ? uy : uz));
            } else {
                if (m == 0)      sh = s15c * ux * uz;
                else if (m == 1) sh = s15c * ux * uy;
                else if (m == 2) sh = s5c * (uy * uy - 0.5f * (ux * ux + uz * uz));
                else if (m == 3) sh = s15c * uy * uz;
                else             sh = 0.5f * s15c * (uz * uz - ux * ux);
            }
        }
        return f * sh;
    };

    float sum0 = 0.f, sum1 = 0.f;
    int e = off0;
    for (; e + 1 < off1; e += 2) { sum0 += term(e); sum1 += term(e + 1); }
    if (e < off1) sum0 += term(e);

    if (j < 60) {
        float cnt = (float)(off1 - off0);
        out[nd * 60 + j] = (sum0 + sum1) * (1.0f / 64.0f) / fmaxf(cnt, 1.0f);
    }
}

extern "C" void kernel_launch(void* const* d_in, const int* in_sizes, int n_in,
                              void* d_out, int out_size, void* d_ws, size_t ws_size,
                              hipStream_t stream)
{
    const float* pos     = (const float*)d_in[0];
    const int*   A       = (const int*)d_in[1];
    const int*   batch   = (const int*)d_in[2];
    const int*   esrc    = (const int*)d_in[3];
    const int*   edst    = (const int*)d_in[4];
    const float* shifts  = (const float*)d_in[5];
    const float* cell    = (const float*)d_in[6];
    const float* emb_tab = (const float*)d_in[7];
    const float* fitW1   = (const float*)d_in[8];
    const float* fitb1   = (const float*)d_in[9];
    const float* fitW2   = (const float*)d_in[10];
    const float* fitb2   = (const float*)d_in[11];
    const float* fitW3   = (const float*)d_in[12];
    const float* fitb3   = (const float*)d_in[13];
    const float* fcW1    = (const float*)d_in[14];
    const float* fcW2    = (const float*)d_in[15];
    const float* fcW3    = (const float*)d_in[16];
    const float* fcW4    = (const float*)d_in[17];

    float* out = (float*)d_out;

    // workspace layout (all 16B-aligned)
    char* W = (char*)d_ws;
    float* Ai      = (float*)W;  W += (size_t)NN * 8 * 4;
    int* sortidx   = (int*)W;    W += (size_t)NE * 4;
    int* hist      = (int*)W;    W += (size_t)NN * 4;
    int* poscnt    = (int*)W;    W += (size_t)NN * 4;
    int* offsets   = (int*)W;    W += (size_t)(NN + 8) * 4;
    float* unit    = (float*)W;  W += (size_t)NE * 3 * 4;
    unsigned short* Bg   = (unsigned short*)W; W += (size_t)131072 * 2;
    unsigned short* Wg   = (unsigned short*)W; W += (size_t)10240 * 2;
    float* featbuf = (float*)W;  W += (size_t)NE * 32 * 4;

    hipMemsetAsync(hist,   0, (size_t)NN * 4, stream);
    hipMemsetAsync(poscnt, 0, (size_t)NN * 4, stream);

    hist_kernel<<<(NE + 255) / 256, 256, 0, stream>>>(edst, hist);
    scan_kernel<<<1, 256, 0, stream>>>(hist, offsets);
    rank_kernel<<<(NE + 255) / 256, 256, 0, stream>>>(edst, offsets, poscnt, sortidx);

    node_mlp_kernel<<<(NN + 255) / 256, 256, 0, stream>>>(
        A, emb_tab, fitW1, fitb1, fitW2, fitb2, fitW3, fitb3, Ai);

    prep_W_kernel<<<10240 / 256, 256, 0, stream>>>(fcW1, fcW2, fcW3, Wg);
    prep_B_kernel<<<131072 / 256, 256, 0, stream>>>(fcW4, Bg);

    edge_fused_kernel<<<NE / 256, 256, 0, stream>>>(
        pos, batch, esrc, edst, shifts, cell, Wg, Bg,
        sortidx, Ai, nullptr, unit, featbuf);

    segment_kernel<<<NN, 64, 0, stream>>>(offsets, featbuf, unit, out);
}

// Round 9
// 241.167 us; speedup vs baseline: 1.6324x; 1.0025x over previous
//
#include <hip/hip_runtime.h>
#include <hip/hip_bf16.h>
#include <math.h>

#define NN 10000
#define NE 131072

typedef __attribute__((ext_vector_type(8))) short short8;
typedef __attribute__((ext_vector_type(4))) float f32x4;

__device__ __forceinline__ float silu_f(float x) {
    return x / (1.0f + __expf(-x));
}

// round-to-nearest-even f32 -> bf16 (finite inputs only)
__device__ __forceinline__ unsigned short f2bf(float f) {
    unsigned int u = __float_as_uint(f);
    u += 0x7FFFu + ((u >> 16) & 1u);
    return (unsigned short)(u >> 16);
}

// packed pair via HW v_cvt_pk_bf16_f32 (x = low half)
__device__ __forceinline__ unsigned int pk_bf16(float lo, float hi) {
    __hip_bfloat162 h = __float22bfloat162_rn(float2{lo, hi});
    return *reinterpret_cast<unsigned int*>(&h);
}

// ---------------------------------------------------------------------------
// K1: MEGA-PREP. One kernel, branch by blockIdx:
//   [0,40)    zero hist
//   [40,80)   node MLP (Ai)
//   [80,120)  prep_W  (fc_W1/2/3 -> bf16 MFMA B-fragments, 10240 elems)
//   [120,632) prep_B  (fc_W4 -> bf16 MFMA fragments, 131072 elems)
//   [632,732) zero out (600000 floats as float4)
// Replaces 2 memsets + 3 kernels: dispatch-count is the current wall.
// ---------------------------------------------------------------------------
__global__ __launch_bounds__(256)
void prep_kernel(const int* __restrict__ A,
                 const float* __restrict__ emb_tab,
                 const float* __restrict__ W1, const float* __restrict__ b1,
                 const float* __restrict__ W2, const float* __restrict__ b2,
                 const float* __restrict__ W3, const float* __restrict__ b3,
                 const float* __restrict__ fcW1,
                 const float* __restrict__ fcW2,
                 const float* __restrict__ fcW3,
                 const float* __restrict__ fcW4,
                 int* __restrict__ hist,
                 float* __restrict__ outg,
                 float* __restrict__ Ai,
                 unsigned short* __restrict__ Wg,
                 unsigned short* __restrict__ Bg)
{
    const int blk = blockIdx.x;
    const int tid = threadIdx.x;

    if (blk < 40) {
        int t = blk * 256 + tid;
        if (t < NN) hist[t] = 0;
    } else if (blk < 80) {
        int n = (blk - 40) * 256 + tid;
        if (n >= NN) return;
        int a = A[n];
        float h[16];
#pragma unroll
        for (int i = 0; i < 16; ++i) h[i] = emb_tab[a * 16 + i];
        float h1[64];
#pragma unroll
        for (int j = 0; j < 64; ++j) h1[j] = b1[j];
#pragma unroll
        for (int i = 0; i < 16; ++i) {
            float hv = h[i];
#pragma unroll
            for (int j = 0; j < 64; ++j) h1[j] += hv * W1[i * 64 + j];
        }
#pragma unroll
        for (int j = 0; j < 64; ++j) h1[j] = silu_f(h1[j]);
        float h2[32];
#pragma unroll
        for (int j = 0; j < 32; ++j) h2[j] = b2[j];
#pragma unroll
        for (int i = 0; i < 64; ++i) {
            float hv = h1[i];
#pragma unroll
            for (int j = 0; j < 32; ++j) h2[j] += hv * W2[i * 32 + j];
        }
#pragma unroll
        for (int j = 0; j < 32; ++j) h2[j] = silu_f(h2[j]);
#pragma unroll
        for (int j = 0; j < 8; ++j) {
            float s = b3[j];
#pragma unroll
            for (int i = 0; i < 32; ++i) s += h2[i] * W3[i * 8 + j];
            Ai[n * 8 + j] = s;
        }
    } else if (blk < 120) {
        // prep_W: 20 frags of 512 bf16. L1 frags 0..3 (K=32 padded from 10),
        // L2 4..11, L3 12..19 (f = base + kf*4 + nt). Element (lane,j):
        //   B[k = kf*32 + (lane>>4)*8 + j][col = nt*16 + (lane&15)]
        int i = (blk - 80) * 256 + tid;   // [0, 10240)
        int j    = i & 7;
        int lane = (i >> 3) & 63;
        int f    = i >> 9;
        int q = lane >> 4, n = lane & 15;
        int L, kf, nt;
        if (f < 4)       { L = 1; kf = 0;             nt = f; }
        else if (f < 12) { L = 2; kf = (f - 4) >> 2;  nt = (f - 4) & 3; }
        else             { L = 3; kf = (f - 12) >> 2; nt = (f - 12) & 3; }
        int k = kf * 32 + q * 8 + j;
        int col = nt * 16 + n;
        float v = 0.0f;
        if (L == 1)      { if (k < 10) v = fcW1[k * 64 + col]; }
        else if (L == 2) v = fcW2[k * 64 + col];
        else             v = fcW3[k * 64 + col];
        Wg[i] = f2bf(v);
    } else if (blk < 632) {
        // prep_B: fragment f=(k*2+h)*2+nt; lane (q,n), j:
        //   B[kdim=q*8+j][col=n] = fcW4[k][uv=h*32+q*8+j][wc=nt*16+n], wc>=28->0
        int i = (blk - 120) * 256 + tid;   // [0, 131072)
        int j    = i & 7;
        int lane = (i >> 3) & 63;
        int nt   = (i >> 9) & 1;
        int h    = (i >> 10) & 1;
        int k    = i >> 11;
        int q = lane >> 4, n = lane & 15;
        int uv = h * 32 + q * 8 + j;
        int wc = nt * 16 + n;
        float v;
        if (wc < 16)      v = fcW4[k * 1792 + uv * 16 + wc];
        else if (wc < 24) v = fcW4[k * 1792 + 1024 + uv * 8 + (wc - 16)];
        else if (wc < 28) v = fcW4[k * 1792 + 1536 + uv * 4 + (wc - 24)];
        else              v = 0.0f;
        Bg[i] = f2bf(v);
    } else {
        // zero out: 600000 floats = 150000 float4
        int t = (blk - 632) * 256 + tid;   // [0, 25600)
        float4 z = float4{0.f, 0.f, 0.f, 0.f};
        for (int r = t; r < 150000; r += 25600)
            ((float4*)outg)[r] = z;
    }
}

// ---------------------------------------------------------------------------
// K2: histogram of edge dst.
// ---------------------------------------------------------------------------
__global__ __launch_bounds__(256)
void hist_kernel(const int* __restrict__ edst, int* __restrict__ hist)
{
    int e = blockIdx.x * 256 + threadIdx.x;
    if (e < NE) atomicAdd(&hist[edst[e]], 1);
}

// ---------------------------------------------------------------------------
// K3: exclusive scan of hist -> offsets (1 block, parallel Hillis-Steele).
// ---------------------------------------------------------------------------
__global__ __launch_bounds__(256)
void scan_kernel(const int* __restrict__ hist, int* __restrict__ offsets)
{
    __shared__ int part[256];
    int tid = threadIdx.x;
    int base = tid * 40, s = 0;
    for (int r = 0; r < 40; ++r) {
        int idx = base + r;
        if (idx < NN) s += hist[idx];
    }
    part[tid] = s;
    __syncthreads();
#pragma unroll
    for (int off = 1; off < 256; off <<= 1) {
        int v = (tid >= off) ? part[tid - off] : 0;
        __syncthreads();
        part[tid] += v;
        __syncthreads();
    }
    int run = part[tid] - s;   // exclusive prefix
    for (int r = 0; r < 40; ++r) {
        int idx = base + r;
        if (idx < NN) { offsets[idx] = run; run += hist[idx]; }
    }
    if (tid == 255) offsets[NN] = run;   // == NE
}

// ---------------------------------------------------------------------------
// K4: rank edges into sorted order. Reuses hist as the per-bin counter
// (atomicSub; hist is dead after scan) — no poscnt buffer / memset.
// ---------------------------------------------------------------------------
__global__ __launch_bounds__(256)
void rank_kernel(const int* __restrict__ edst, const int* __restrict__ offsets,
                 int* __restrict__ hist, int* __restrict__ sortidx)
{
    int e = blockIdx.x * 256 + threadIdx.x;
    if (e >= NE) return;
    int d = edst[e];
    int old = atomicSub(&hist[d], 1);
    sortidx[offsets[d] + old - 1] = e;
}

// ---------------------------------------------------------------------------
// K5: FULLY FUSED edge pipeline: geometry + radial MLP (MFMA) + P-operand
// contraction + segmented sh-weighted node reduction (no featbuf/unit
// round-trip, no segment kernel).
// 512 blocks x 4 waves x 64 sorted edges. w3 and feat never leave LDS.
// Epilogue: per-wave segmented reduce over the sorted window; node partials
// (scaled by 1/(64*cnt)) atomicAdd'd to out — sorted order => ~5 distinct
// nodes per 64-edge window => ~630k atomics total (vs 8M in round 3).
// LDS: Wbuf(20K) U B-dbuf(16K) + act 4x8.5K + sd 2K + unit 3K = 59 KB.
// ---------------------------------------------------------------------------
__global__ __launch_bounds__(256, 2)
void edge_fused_kernel(const float* __restrict__ pos,
                       const int* __restrict__ batch,
                       const int* __restrict__ esrc,
                       const int* __restrict__ edst,
                       const float* __restrict__ shifts,
                       const float* __restrict__ cell,
                       const unsigned short* __restrict__ Wg,
                       const unsigned short* __restrict__ Bg,
                       const int* __restrict__ sortidx,
                       const float* __restrict__ Ai,
                       const int* __restrict__ offsets,
                       float* __restrict__ out_g)
{
    __shared__ __align__(16) unsigned char  WBs[20480];       // Wbuf(20KB) U Bs[2][8KB]
    __shared__ __align__(16) unsigned short actb[4][64 * 68]; // 4 x 8.5 KB
    __shared__ int   sdbuf[512];                              // [edge][2] = s,d
    __shared__ float unitb[4][192];                           // [wave][edge*3]

    const int tid  = threadIdx.x;
    const int wave = tid >> 6;
    const int lane = tid & 63;
    const int q    = lane >> 4;
    const int n    = lane & 15;
    const int i0   = blockIdx.x * 256 + wave * 64;
    const int i    = i0 + lane;

    // ---- stage weight fragments (block-shared, 1280 x 16B) ----
#pragma unroll
    for (int it = 0; it < 5; ++it) {
        int idx = it * 256 + tid;
        const unsigned short* gp = Wg + idx * 8;
        unsigned char* lb = WBs + (it * 256 + wave * 64) * 16;
        __builtin_amdgcn_global_load_lds(
            (const __attribute__((address_space(1))) unsigned int*)gp,
            (__attribute__((address_space(3))) unsigned int*)lb, 16, 0, 0);
    }

    unsigned short* actw = actb[wave];

    // ---- geometry (1 lane = 1 edge) ----
    int e = sortidx[i];
    int s = esrc[e], d = edst[e];
    sdbuf[2 * (wave * 64 + lane)]     = s;
    sdbuf[2 * (wave * 64 + lane) + 1] = d;
    int b = batch[s];
    const float* C = cell + b * 9;
    float sx = shifts[e * 3 + 0], sy = shifts[e * 3 + 1], sz = shifts[e * 3 + 2];
    float vx = pos[d * 3 + 0] - pos[s * 3 + 0] + sx * C[0] + sy * C[3] + sz * C[6];
    float vy = pos[d * 3 + 1] - pos[s * 3 + 1] + sx * C[1] + sy * C[4] + sz * C[7];
    float vz = pos[d * 3 + 2] - pos[s * 3 + 2] + sx * C[2] + sy * C[5] + sz * C[8];
    float len = sqrtf(vx * vx + vy * vy + vz * vz);
    float inv = 1.0f / fmaxf(len, 1e-9f);
    unitb[wave][lane * 3 + 0] = vx * inv;
    unitb[wave][lane * 3 + 1] = vy * inv;
    unitb[wave][lane * 3 + 2] = vz * inv;

    // soft_one_hot (sqrt(10) cancels with fc_W1's /sqrt(10))
    float embv[10];
    float base = len * 2.75f;
#pragma unroll
    for (int ii = 0; ii < 10; ++ii) {
        float dd = base - (float)(ii + 1);
        embv[ii] = __expf(-dd * dd) * (1.0f / 1.12f);
    }
    // pack emb -> act row `lane`, k in [0,32) (zero-padded past 10)
    {
        unsigned int u0 = pk_bf16(embv[0], embv[1]);
        unsigned int u1 = pk_bf16(embv[2], embv[3]);
        unsigned int u2 = pk_bf16(embv[4], embv[5]);
        unsigned int u3 = pk_bf16(embv[6], embv[7]);
        unsigned int u4 = pk_bf16(embv[8], embv[9]);
        uint2* arow = (uint2*)&actw[lane * 68];
        arow[0] = uint2{u0, u1};
        arow[1] = uint2{u2, u3};
        arow[2] = uint2{u4, 0u};
        arow[3] = uint2{0u, 0u};
        arow[4] = uint2{0u, 0u};
        arow[5] = uint2{0u, 0u};
        arow[6] = uint2{0u, 0u};
        arow[7] = uint2{0u, 0u};
    }

    __syncthreads();   // weights staged; sd written

    union AF { unsigned int u[4]; short8 s8; };
    const f32x4 Z4 = (f32x4){0.f, 0.f, 0.f, 0.f};
    const unsigned short* Wbuf = (const unsigned short*)WBs;

    auto loadA = [&](int t, int kf) -> AF {
        const unsigned short* ap = &actw[(t * 16 + n) * 68 + kf * 32 + q * 8];
        uint2 a = *(const uint2*)ap;
        uint2 c = *(const uint2*)(ap + 4);
        AF f; f.u[0] = a.x; f.u[1] = a.y; f.u[2] = c.x; f.u[3] = c.y;
        return f;
    };
    auto loadW = [&](int f) -> short8 {
        return *(const short8*)&Wbuf[(f * 64 + lane) * 8];
    };

    // ---- layer 1: K=32 (padded emb), N=64 ----
    {
        AF A1[4];
#pragma unroll
        for (int t = 0; t < 4; ++t) A1[t] = loadA(t, 0);
#pragma unroll
        for (int nt = 0; nt < 4; ++nt) {
            short8 W0 = loadW(nt);
            f32x4 Cc[4];
#pragma unroll
            for (int t = 0; t < 4; ++t)
                Cc[t] = __builtin_amdgcn_mfma_f32_16x16x32_bf16(A1[t].s8, W0, Z4, 0, 0, 0);
#pragma unroll
            for (int t = 0; t < 4; ++t)
#pragma unroll
                for (int r = 0; r < 4; ++r)
                    actw[(t * 16 + q * 4 + r) * 68 + nt * 16 + n] = f2bf(silu_f(Cc[t][r]));
        }
    }

    // ---- layer 2: K=64 ----
    {
        AF A2[4][2];
#pragma unroll
        for (int t = 0; t < 4; ++t)
#pragma unroll
            for (int kf = 0; kf < 2; ++kf) A2[t][kf] = loadA(t, kf);
#pragma unroll
        for (int nt = 0; nt < 4; ++nt) {
            short8 Wk0 = loadW(4 + nt);
            short8 Wk1 = loadW(8 + nt);
            f32x4 Cc[4];
#pragma unroll
            for (int t = 0; t < 4; ++t) {
                Cc[t] = __builtin_amdgcn_mfma_f32_16x16x32_bf16(A2[t][0].s8, Wk0, Z4, 0, 0, 0);
                Cc[t] = __builtin_amdgcn_mfma_f32_16x16x32_bf16(A2[t][1].s8, Wk1, Cc[t], 0, 0, 0);
            }
#pragma unroll
            for (int t = 0; t < 4; ++t)
#pragma unroll
                for (int r = 0; r < 4; ++r)
                    actw[(t * 16 + q * 4 + r) * 68 + nt * 16 + n] = f2bf(silu_f(Cc[t][r] * 0.125f));
        }
    }

    // ---- layer 3: K=64, epilogue -> w3 transposed [k][edge] in actw ----
    {
        AF A3[4][2];
#pragma unroll
        for (int t = 0; t < 4; ++t)
#pragma unroll
            for (int kf = 0; kf < 2; ++kf) A3[t][kf] = loadA(t, kf);
#pragma unroll
        for (int nt = 0; nt < 4; ++nt) {
            short8 Wk0 = loadW(12 + nt);
            short8 Wk1 = loadW(16 + nt);
            f32x4 Cc[4];
#pragma unroll
            for (int t = 0; t < 4; ++t) {
                Cc[t] = __builtin_amdgcn_mfma_f32_16x16x32_bf16(A3[t][0].s8, Wk0, Z4, 0, 0, 0);
                Cc[t] = __builtin_amdgcn_mfma_f32_16x16x32_bf16(A3[t][1].s8, Wk1, Cc[t], 0, 0, 0);
            }
#pragma unroll
            for (int t = 0; t < 4; ++t)
#pragma unroll
                for (int r = 0; r < 4; ++r)
                    actw[(nt * 16 + n) * 68 + t * 16 + q * 4 + r] = f2bf(silu_f(Cc[t][r] * 0.125f));
        }
    }

    __syncthreads();   // all waves done with Wbuf -> WBs reusable as B dbuf

    // B chunk stager: chunk c covers k in {2c, 2c+1}: 8 frags, 8 KB
    auto stageB = [&](int c, int buf) {
#pragma unroll
        for (int it = 0; it < 2; ++it) {
            int idx = it * 256 + tid;
            const unsigned char* gp = ((const unsigned char*)Bg) + c * 8192 + idx * 16;
            unsigned char* lb = WBs + buf * 8192 + (it * 256 + wave * 64) * 16;
            __builtin_amdgcn_global_load_lds(
                (const __attribute__((address_space(1))) unsigned int*)gp,
                (__attribute__((address_space(3))) unsigned int*)lb, 16, 0, 0);
        }
    };
    stageB(0, 0);

    // k-invariant P fragments: P[e, uv=h*32+q*8+j] = As[h*4+q]*Ad[j]
    AF P[4][2];
#pragma unroll
    for (int t = 0; t < 4; ++t) {
        int eL = wave * 64 + t * 16 + n;
        int ss = sdbuf[2 * eL];
        int dd = sdbuf[2 * eL + 1];
        float As0 = Ai[ss * 8 + q];
        float As1 = Ai[ss * 8 + 4 + q];
        float4 d0 = *(const float4*)&Ai[dd * 8];
        float4 d1 = *(const float4*)&Ai[dd * 8 + 4];
        float Ad[8] = {d0.x, d0.y, d0.z, d0.w, d1.x, d1.y, d1.z, d1.w};
#pragma unroll
        for (int h = 0; h < 2; ++h) {
            float s0 = h ? As1 : As0;
            P[t][h].u[0] = pk_bf16(s0 * Ad[0], s0 * Ad[1]);
            P[t][h].u[1] = pk_bf16(s0 * Ad[2], s0 * Ad[3]);
            P[t][h].u[2] = pk_bf16(s0 * Ad[4], s0 * Ad[5]);
            P[t][h].u[3] = pk_bf16(s0 * Ad[6], s0 * Ad[7]);
        }
    }

    f32x4 out[4][2];
#pragma unroll
    for (int t = 0; t < 4; ++t)
#pragma unroll
        for (int nt = 0; nt < 2; ++nt)
            out[t][nt] = (f32x4){0.f, 0.f, 0.f, 0.f};

    __syncthreads();   // chunk 0 resident

#pragma unroll 1
    for (int c = 0; c < 32; ++c) {
        int cur = c & 1;
        if (c < 31) stageB(c + 1, cur ^ 1);
#pragma unroll
        for (int kk = 0; kk < 2; ++kk) {
            int k = c * 2 + kk;
            short8 Bf[2][2];
#pragma unroll
            for (int h = 0; h < 2; ++h)
#pragma unroll
                for (int nt = 0; nt < 2; ++nt)
                    Bf[h][nt] = *(const short8*)(WBs + cur * 8192 +
                                 ((kk * 2 + h) * 2 + nt) * 1024 + lane * 16);
#pragma unroll
            for (int t = 0; t < 4; ++t) {
                uint2 v = *(const uint2*)&actw[k * 68 + t * 16 + q * 4];
                float w0 = __uint_as_float(v.x << 16);
                float w1 = __uint_as_float(v.x & 0xFFFF0000u);
                float w2 = __uint_as_float(v.y << 16);
                float w3 = __uint_as_float(v.y & 0xFFFF0000u);
#pragma unroll
                for (int nt = 0; nt < 2; ++nt) {
                    f32x4 Q = __builtin_amdgcn_mfma_f32_16x16x32_bf16(
                        P[t][0].s8, Bf[0][nt], Z4, 0, 0, 0);
                    Q = __builtin_amdgcn_mfma_f32_16x16x32_bf16(
                        P[t][1].s8, Bf[1][nt], Q, 0, 0, 0);
                    out[t][nt][0] += w0 * Q[0];
                    out[t][nt][1] += w1 * Q[1];
                    out[t][nt][2] += w2 * Q[2];
                    out[t][nt][3] += w3 * Q[3];
                }
            }
        }
        __syncthreads();
    }

    // ---- epilogue: feat rows -> LDS (stride 33, conflict-free), then
    // per-wave segmented sh-weighted reduction over the sorted window ----
    float* featL = (float*)actw;   // [64][33] fp32 = 8448 B (actw is 8704 B)
#pragma unroll
    for (int t = 0; t < 4; ++t) {
#pragma unroll
        for (int r = 0; r < 4; ++r) {
            int row = t * 16 + q * 4 + r;
            featL[row * 33 + n]      = out[t][0][r];
            featL[row * 33 + 16 + n] = out[t][1][r];
        }
    }
    // same-wave ds write->read: lockstep + compiler lgkmcnt, no barrier needed

    if (lane < 60) {
        const float s3c  = 1.7320508075688772f;
        const float s5c  = 2.2360679774997896f;
        const float s15c = 3.872983346207417f;
        int j = lane;
        int cc = 0, mode = 0, m = 0;
        if (j < 16)      { cc = j; mode = 0; }
        else if (j < 40) { int w = (j - 16) / 3; m = (j - 16) % 3; cc = 16 + w; mode = 1; }
        else             { int w = (j - 40) / 5; m = (j - 40) % 5; cc = 24 + w; mode = 2; }

        int cur_d = sdbuf[2 * (wave * 64) + 1];
        float acc = 0.f;
        for (int e2 = 0; e2 < 64; ++e2) {
            int d_e = sdbuf[2 * (wave * 64 + e2) + 1];   // wave-uniform
            if (d_e != cur_d) {
                int cnt = offsets[cur_d + 1] - offsets[cur_d];
                atomicAdd(&out_g[cur_d * 60 + j], acc * (1.0f / 64.0f) / (float)cnt);
                acc = 0.f;
                cur_d = d_e;
            }
            float f = featL[e2 * 33 + cc];
            float sh = 1.f;
            if (mode != 0) {
                float ux = unitb[wave][e2 * 3 + 0];
                float uy = unitb[wave][e2 * 3 + 1];
                float uz = unitb[wave][e2 * 3 + 2];
                if (mode == 1) {
                    sh = s3c * (m == 0 ? ux : (m == 1 ? uy : uz));
                } else {
                    if (m == 0)      sh = s15c * ux * uz;
                    else if (m == 1) sh = s15c * ux * uy;
                    else if (m == 2) sh = s5c * (uy * uy - 0.5f * (ux * ux + uz * uz));
                    else if (m == 3) sh = s15c * uy * uz;
                    else             sh = 0.5f * s15c * (uz * uz - ux * ux);
                }
            }
            acc += f * sh;
        }
        int cnt = offsets[cur_d + 1] - offsets[cur_d];
        atomicAdd(&out_g[cur_d * 60 + j], acc * (1.0f / 64.0f) / (float)cnt);
    }
}

extern "C" void kernel_launch(void* const* d_in, const int* in_sizes, int n_in,
                              void* d_out, int out_size, void* d_ws, size_t ws_size,
                              hipStream_t stream)
{
    const float* pos     = (const float*)d_in[0];
    const int*   A       = (const int*)d_in[1];
    const int*   batch   = (const int*)d_in[2];
    const int*   esrc    = (const int*)d_in[3];
    const int*   edst    = (const int*)d_in[4];
    const float* shifts  = (const float*)d_in[5];
    const float* cell    = (const float*)d_in[6];
    const float* emb_tab = (const float*)d_in[7];
    const float* fitW1   = (const float*)d_in[8];
    const float* fitb1   = (const float*)d_in[9];
    const float* fitW2   = (const float*)d_in[10];
    const float* fitb2   = (const float*)d_in[11];
    const float* fitW3   = (const float*)d_in[12];
    const float* fitb3   = (const float*)d_in[13];
    const float* fcW1    = (const float*)d_in[14];
    const float* fcW2    = (const float*)d_in[15];
    const float* fcW3    = (const float*)d_in[16];
    const float* fcW4    = (const float*)d_in[17];

    float* out = (float*)d_out;

    // workspace layout (all 16B-aligned)
    char* W = (char*)d_ws;
    float* Ai      = (float*)W;  W += (size_t)NN * 8 * 4;
    int* sortidx   = (int*)W;    W += (size_t)NE * 4;
    int* hist      = (int*)W;    W += (size_t)NN * 4;
    int* offsets   = (int*)W;    W += (size_t)(NN + 8) * 4;
    unsigned short* Bg = (unsigned short*)W; W += (size_t)131072 * 2;
    unsigned short* Wg = (unsigned short*)W; W += (size_t)10240 * 2;

    prep_kernel<<<732, 256, 0, stream>>>(
        A, emb_tab, fitW1, fitb1, fitW2, fitb2, fitW3, fitb3,
        fcW1, fcW2, fcW3, fcW4, hist, out, Ai, Wg, Bg);

    hist_kernel<<<NE / 256, 256, 0, stream>>>(edst, hist);
    scan_kernel<<<1, 256, 0, stream>>>(hist, offsets);
    rank_kernel<<<NE / 256, 256, 0, stream>>>(edst, offsets, hist, sortidx);

    edge_fused_kernel<<<NE / 256, 256, 0, stream>>>(
        pos, batch, esrc, edst, shifts, cell, Wg, Bg,
        sortidx, Ai, offsets, out);
}